// Round 1
// baseline (2719.872 us; speedup 1.0000x reference)
//
#include <hip/hip_runtime.h>
#include <math.h>

// ---------------- problem constants ----------------
#define NN    36864        // N = B*V
#define F0    1025
#define H1D   256
#define H2D   64
#define VV    36
#define SS    12
#define BSZ   1024         // N / V
#define BN_EPS 1e-5f

// ---------------- utility ----------------
__global__ void k_zero(float* __restrict__ p, int n) {
    int i = blockIdx.x * blockDim.x + threadIdx.x;
    if (i < n) p[i] = 0.f;
}

// deg[i] = number of edges with src == i
__global__ void k_deg(const int* __restrict__ src, int E, float* __restrict__ deg) {
    int e = blockIdx.x * blockDim.x + threadIdx.x;
    if (e < E) atomicAdd(&deg[src[e]], 1.f);
}

__device__ __forceinline__ float dinv_f(float d) {
    return d > 0.f ? rsqrtf(fmaxf(d, 1.f)) : 0.f;
}

// Adj[block][dstLocal][srcLocal] += w   (edges are block-local by construction)
__global__ void k_scatter(const int* __restrict__ src, const int* __restrict__ dst, int E,
                          const float* __restrict__ deg, float* __restrict__ Adj) {
    int e = blockIdx.x * blockDim.x + threadIdx.x;
    if (e >= E) return;
    int s = src[e], d = dst[e];
    float w = -dinv_f(deg[s]) * dinv_f(deg[d]);
    int blk = s / VV;
    atomicAdd(&Adj[(size_t)blk * (VV * VV) + (d - blk * VV) * VV + (s - blk * VV)], w);
}

// ---------------- GEMM1: H = (x + Temb[c] + Semb[s]) @ [W0|W1] ----------------
// M=36864, K=1025, Ncols=512 (H0: cols 0..255, H1: cols 256..511)
// grid (288, 4), block 256; 128x128 tile, TK=16, 8x8 per-thread accum.
__global__ __launch_bounds__(256) void k_gemm1(
    const float* __restrict__ x, const float* __restrict__ Temb, const float* __restrict__ Semb,
    const float* __restrict__ W0, const float* __restrict__ W1,
    float* __restrict__ H0, float* __restrict__ H1) {
    __shared__ __align__(16) float As[16 * 128];
    __shared__ __align__(16) float Bs[16 * 128];
    const int tid = threadIdx.x;
    const int bm = blockIdx.x;
    const int by = blockIdx.y;                 // 0,1 -> W0/H0 ; 2,3 -> W1/H1
    const float* W = (by < 2) ? W0 : W1;
    float* Hout = (by < 2) ? H0 : H1;
    const int cbase = (by & 1) * 128;

    // A loading: thread -> (row = tid/2, kseg = (tid&1)*8)
    const int arow = tid >> 1;
    const int akseg = (tid & 1) * 8;
    const int gRow = bm * 128 + arow;
    const int lv = gRow % VV;
    const float* px = x + (size_t)gRow * F0;
    const float* pt = Temb + (size_t)(lv / SS) * F0;
    const float* ps = Semb + (size_t)(lv % SS) * F0;

    // B loading: thread -> (krow = tid/16, cseg = (tid&15)*8)
    const int bk = tid >> 4;
    const int bcs = (tid & 15) * 8;

    // compute mapping: 8x8 block at (rb, cb2)
    const int rb = (tid >> 4) * 8;
    const int cb2 = (tid & 15) * 8;

    float acc[8][8];
#pragma unroll
    for (int i = 0; i < 8; ++i)
#pragma unroll
        for (int j = 0; j < 8; ++j) acc[i][j] = 0.f;

    for (int k0 = 0; k0 < F0; k0 += 16) {
#pragma unroll
        for (int i = 0; i < 8; ++i) {
            int kk = k0 + akseg + i;
            float v = 0.f;
            if (kk < F0) v = px[kk] + pt[kk] + ps[kk];
            As[(akseg + i) * 128 + arow] = v;
        }
        {
            int kk = k0 + bk;
#pragma unroll
            for (int i = 0; i < 8; ++i) {
                float v = 0.f;
                if (kk < F0) v = W[(size_t)kk * H1D + cbase + bcs + i];
                Bs[bk * 128 + bcs + i] = v;
            }
        }
        __syncthreads();
#pragma unroll
        for (int kk = 0; kk < 16; ++kk) {
            float4 a0 = *reinterpret_cast<const float4*>(&As[kk * 128 + rb]);
            float4 a1 = *reinterpret_cast<const float4*>(&As[kk * 128 + rb + 4]);
            float4 b0 = *reinterpret_cast<const float4*>(&Bs[kk * 128 + cb2]);
            float4 b1 = *reinterpret_cast<const float4*>(&Bs[kk * 128 + cb2 + 4]);
            float a[8] = {a0.x, a0.y, a0.z, a0.w, a1.x, a1.y, a1.z, a1.w};
            float b[8] = {b0.x, b0.y, b0.z, b0.w, b1.x, b1.y, b1.z, b1.w};
#pragma unroll
            for (int i = 0; i < 8; ++i)
#pragma unroll
                for (int j = 0; j < 8; ++j) acc[i][j] += a[i] * b[j];
        }
        __syncthreads();
    }
#pragma unroll
    for (int i = 0; i < 8; ++i) {
        int r = bm * 128 + rb + i;
        float* o = Hout + (size_t)r * H1D + cbase + cb2;
#pragma unroll
        for (int j = 0; j < 8; ++j) o[j] = acc[i][j];
    }
}

// ---------------- cheb combine layer1: Y = H0 + Adj @ H1 + b (in-place into H0) ----
__global__ __launch_bounds__(256) void k_combine1(
    const float* __restrict__ Adj, const float* __restrict__ H1v,
    const float* __restrict__ bias, float* __restrict__ Y) {
    __shared__ float Adj_s[VV * VV];
    __shared__ float H1_s[VV * H1D];
    int b = blockIdx.x, t = threadIdx.x;
    for (int e = t; e < VV * VV; e += 256) Adj_s[e] = Adj[(size_t)b * VV * VV + e];
    const float* h1b = H1v + (size_t)b * VV * H1D;
    for (int e = t; e < VV * H1D; e += 256) H1_s[e] = h1b[e];
    __syncthreads();
    float bv = bias[t];
    float* yb = Y + (size_t)b * VV * H1D;
    for (int r = 0; r < VV; ++r) {
        float acc = yb[r * H1D + t] + bv;
#pragma unroll
        for (int j = 0; j < VV; ++j) acc += Adj_s[r * VV + j] * H1_s[j * H1D + t];
        yb[r * H1D + t] = acc;
    }
}

// ---------------- BN stats (sum, sumsq per column) ----------------
__global__ __launch_bounds__(256) void k_stats256(const float* __restrict__ Y, float* __restrict__ st) {
    int t = threadIdx.x;
    int r0 = blockIdx.x * 256;
    float s = 0.f, s2 = 0.f;
    for (int i = 0; i < 256; ++i) {
        float v = Y[(size_t)(r0 + i) * H1D + t];
        s += v; s2 += v * v;
    }
    atomicAdd(&st[t], s);
    atomicAdd(&st[H1D + t], s2);
}

__global__ __launch_bounds__(256) void k_stats64(const float* __restrict__ Y, float* __restrict__ st) {
    int t = threadIdx.x;
    int c = t & 63, rg = t >> 6;
    int r0 = blockIdx.x * 256;
    float s = 0.f, s2 = 0.f;
    for (int i = 0; i < 64; ++i) {
        float v = Y[(size_t)(r0 + rg + 4 * i) * H2D + c];
        s += v; s2 += v * v;
    }
    atomicAdd(&st[c], s);
    atomicAdd(&st[H2D + c], s2);
}

// coef[t] = g*rsqrt(var+eps); coef[H+t] = bt - mu*coef[t]
__global__ void k_finalize(const float* __restrict__ st, const float* __restrict__ g,
                           const float* __restrict__ bt, float* __restrict__ coef, int H) {
    int t = threadIdx.x;
    if (t >= H) return;
    float mu = st[t] / (float)NN;
    float var = st[H + t] / (float)NN - mu * mu;
    float sA = g[t] * rsqrtf(var + BN_EPS);
    coef[t] = sA;
    coef[H + t] = bt[t] - mu * sA;
}

// ---------------- GEMM2: G = relu(Y*sA+sB) @ [W0b|W1b] ----------------
// M=36864, K=256, Ncols=128 (G0 cols 0..63, G1 cols 64..127). grid (288,1).
__global__ __launch_bounds__(256) void k_gemm2(
    const float* __restrict__ Y, const float* __restrict__ coef,
    const float* __restrict__ W0b, const float* __restrict__ W1b,
    float* __restrict__ G0, float* __restrict__ G1) {
    __shared__ __align__(16) float As[16 * 128];
    __shared__ __align__(16) float Bs[16 * 128];
    const int tid = threadIdx.x;
    const int bm = blockIdx.x;

    const int arow = tid >> 1;
    const int akseg = (tid & 1) * 8;
    const int gRow = bm * 128 + arow;
    const float* py = Y + (size_t)gRow * H1D;

    const int bk = tid >> 4;
    const int bcs = (tid & 15) * 8;

    const int rb = (tid >> 4) * 8;
    const int cb2 = (tid & 15) * 8;

    float acc[8][8];
#pragma unroll
    for (int i = 0; i < 8; ++i)
#pragma unroll
        for (int j = 0; j < 8; ++j) acc[i][j] = 0.f;

    for (int k0 = 0; k0 < H1D; k0 += 16) {
#pragma unroll
        for (int i = 0; i < 8; ++i) {
            int kk = k0 + akseg + i;
            float v = py[kk];
            v = fmaxf(fmaf(v, coef[kk], coef[H1D + kk]), 0.f);
            As[(akseg + i) * 128 + arow] = v;
        }
        {
            int kk = k0 + bk;
#pragma unroll
            for (int i = 0; i < 8; ++i) {
                int col = bcs + i;
                float v = (col < 64) ? W0b[(size_t)kk * H2D + col]
                                     : W1b[(size_t)kk * H2D + col - 64];
                Bs[bk * 128 + col] = v;
            }
        }
        __syncthreads();
#pragma unroll
        for (int kk = 0; kk < 16; ++kk) {
            float4 a0 = *reinterpret_cast<const float4*>(&As[kk * 128 + rb]);
            float4 a1 = *reinterpret_cast<const float4*>(&As[kk * 128 + rb + 4]);
            float4 b0 = *reinterpret_cast<const float4*>(&Bs[kk * 128 + cb2]);
            float4 b1 = *reinterpret_cast<const float4*>(&Bs[kk * 128 + cb2 + 4]);
            float a[8] = {a0.x, a0.y, a0.z, a0.w, a1.x, a1.y, a1.z, a1.w};
            float b[8] = {b0.x, b0.y, b0.z, b0.w, b1.x, b1.y, b1.z, b1.w};
#pragma unroll
            for (int i = 0; i < 8; ++i)
#pragma unroll
                for (int j = 0; j < 8; ++j) acc[i][j] += a[i] * b[j];
        }
        __syncthreads();
    }
#pragma unroll
    for (int i = 0; i < 8; ++i) {
        int r = bm * 128 + rb + i;
        float* o = (cb2 < 64) ? (G0 + (size_t)r * H2D + cb2)
                              : (G1 + (size_t)r * H2D + (cb2 - 64));
#pragma unroll
        for (int j = 0; j < 8; ++j) o[j] = acc[i][j];
    }
}

// ---------------- cheb combine layer2 (in-place into G0) ----------------
__global__ __launch_bounds__(256) void k_combine2(
    const float* __restrict__ Adj, const float* __restrict__ G1v,
    const float* __restrict__ bias, float* __restrict__ Y2) {
    __shared__ float Adj_s[VV * VV];
    __shared__ float G1_s[VV * H2D];
    int b = blockIdx.x, t = threadIdx.x;
    for (int e = t; e < VV * VV; e += 256) Adj_s[e] = Adj[(size_t)b * VV * VV + e];
    const float* g1b = G1v + (size_t)b * VV * H2D;
    for (int e = t; e < VV * H2D; e += 256) G1_s[e] = g1b[e];
    __syncthreads();
    int c = t & 63, rg = t >> 6;
    float bv = bias[c];
    float* yb = Y2 + (size_t)b * VV * H2D;
    for (int r = rg; r < VV; r += 4) {
        float acc = yb[r * H2D + c] + bv;
#pragma unroll
        for (int j = 0; j < VV; ++j) acc += Adj_s[r * VV + j] * G1_s[j * H2D + c];
        yb[r * H2D + c] = acc;
    }
}

// ---------------- pool: rows [b*36+12, b*36+24) -> max | mean ----------------
__global__ __launch_bounds__(64) void k_pool(const float* __restrict__ Y2,
                                             const float* __restrict__ coef,
                                             float* __restrict__ feat) {
    int b = blockIdx.x, c = threadIdx.x;
    float sA = coef[c], sB = coef[H2D + c];
    float mx = -1e30f, sm = 0.f;
    const float* yb = Y2 + ((size_t)b * VV + SS) * H2D + c;
#pragma unroll
    for (int i = 0; i < SS; ++i) {
        float v = fmaxf(fmaf(yb[i * H2D], sA, sB), 0.f);
        mx = fmaxf(mx, v);
        sm += v;
    }
    feat[b * 128 + c] = mx;
    feat[b * 128 + 64 + c] = sm * (1.f / 12.f);
}

// ---------------- heads: outF, outD, fusion, out ----------------
__global__ __launch_bounds__(128) void k_heads(
    const float* __restrict__ featF, const float* __restrict__ featD,
    const float* __restrict__ WlinF, const float* __restrict__ blinF,
    const float* __restrict__ WlinD, const float* __restrict__ blinD,
    const float* __restrict__ Wlin, const float* __restrict__ blin,
    float* __restrict__ out) {
    __shared__ float sF[128], sD[128], lg[24];
    int r = blockIdx.x, t = threadIdx.x;
    sF[t] = featF[r * 128 + t];
    sD[t] = featD[r * 128 + t];
    __syncthreads();
    // fusion = concat(featF, featD)
    float* fus = out + 10240 + (size_t)r * 256;
    fus[t] = sF[t];
    fus[128 + t] = sD[t];
    if (t < 5) {
        float a = blinF[t];
        for (int k = 0; k < 128; ++k) a += sF[k] * WlinF[k * 5 + t];
        lg[t] = a;
    } else if (t >= 8 && t < 13) {
        int j = t - 8;
        float a = blinD[j];
        for (int k = 0; k < 128; ++k) a += sD[k] * WlinD[k * 5 + j];
        lg[8 + j] = a;
    } else if (t >= 16 && t < 21) {
        int j = t - 16;
        float a = blin[j];
        for (int k = 0; k < 128; ++k) a += sF[k] * Wlin[k * 5 + j];
        for (int k = 0; k < 128; ++k) a += sD[k] * Wlin[(128 + k) * 5 + j];
        lg[16 + j] = a;
    }
    __syncthreads();
    if (t < 15) {
        int grp = t / 5, j = t % 5;
        const float* l = &lg[grp * 8];
        float m = l[0];
#pragma unroll
        for (int k = 1; k < 5; ++k) m = fmaxf(m, l[k]);
        float den = 0.f;
#pragma unroll
        for (int k = 0; k < 5; ++k) den += expf(l[k] - m);
        float v = expf(l[j] - m) / den;
        float* dst = (grp == 0) ? out : (grp == 1 ? out + 5120 : out + 272384);
        dst[r * 5 + j] = v;
    }
}

// ---------------- launch ----------------
extern "C" void kernel_launch(void* const* d_in, const int* in_sizes, int n_in,
                              void* d_out, int out_size, void* d_ws, size_t ws_size,
                              hipStream_t stream) {
    const float* xF    = (const float*)d_in[0];
    const float* xD    = (const float*)d_in[1];
    const int*   eiF   = (const int*)d_in[2];
    const int*   eiD   = (const int*)d_in[3];
    const float* TembF = (const float*)d_in[4];
    const float* SembF = (const float*)d_in[5];
    const float* TembD = (const float*)d_in[6];
    const float* SembD = (const float*)d_in[7];
    const float* W0F1  = (const float*)d_in[8];
    const float* W1F1  = (const float*)d_in[9];
    const float* bF1   = (const float*)d_in[10];
    const float* gF1   = (const float*)d_in[11];
    const float* btF1  = (const float*)d_in[12];
    const float* W0F2  = (const float*)d_in[13];
    const float* W1F2  = (const float*)d_in[14];
    const float* bF2   = (const float*)d_in[15];
    const float* gF2   = (const float*)d_in[16];
    const float* btF2  = (const float*)d_in[17];
    const float* W0D1  = (const float*)d_in[18];
    const float* W1D1  = (const float*)d_in[19];
    const float* bD1   = (const float*)d_in[20];
    const float* gD1   = (const float*)d_in[21];
    const float* btD1  = (const float*)d_in[22];
    const float* W0D2  = (const float*)d_in[23];
    const float* W1D2  = (const float*)d_in[24];
    const float* bD2   = (const float*)d_in[25];
    const float* gD2   = (const float*)d_in[26];
    const float* btD2  = (const float*)d_in[27];
    const float* WlinF = (const float*)d_in[28];
    const float* blinF = (const float*)d_in[29];
    const float* WlinD = (const float*)d_in[30];
    const float* blinD = (const float*)d_in[31];
    const float* Wlin  = (const float*)d_in[32];
    const float* blin  = (const float*)d_in[33];

    const int E = in_sizes[2] / 2;   // 589824 edges per branch

    // workspace layout (floats); big buffers shared between the two branches
    float* ws = (float*)d_ws;
    size_t o = 0;
    float* H0   = ws + o; o += (size_t)NN * H1D;      // 9,437,184  (also Y1)
    float* H1v  = ws + o; o += (size_t)NN * H1D;
    float* G0   = ws + o; o += (size_t)NN * H2D;      // also Y2
    float* G1v  = ws + o; o += (size_t)NN * H2D;
    float* Adj  = ws + o; o += (size_t)BSZ * VV * VV; // -- zero span start
    float* deg  = ws + o; o += NN;
    float* st1  = ws + o; o += 2 * H1D;
    float* st2  = ws + o; o += 2 * H2D;               // -- zero span end
    float* coef1 = ws + o; o += 2 * H1D;
    float* coef2 = ws + o; o += 2 * H2D;
    float* featF = ws + o; o += (size_t)BSZ * 128;
    float* featD = ws + o; o += (size_t)BSZ * 128;

    const int zeroN = BSZ * VV * VV + NN + 2 * H1D + 2 * H2D; // Adj..st2 contiguous

    auto branch = [&](const float* x, const int* ei,
                      const float* Temb, const float* Semb,
                      const float* W0a, const float* W1a, const float* ba,
                      const float* ga, const float* bta,
                      const float* W0b, const float* W1b, const float* bb,
                      const float* gb, const float* btb, float* feat) {
        k_zero<<<(zeroN + 255) / 256, 256, 0, stream>>>(Adj, zeroN);
        k_deg<<<(E + 255) / 256, 256, 0, stream>>>(ei, E, deg);
        k_scatter<<<(E + 255) / 256, 256, 0, stream>>>(ei, ei + E, E, deg, Adj);
        k_gemm1<<<dim3(288, 4), 256, 0, stream>>>(x, Temb, Semb, W0a, W1a, H0, H1v);
        k_combine1<<<BSZ, 256, 0, stream>>>(Adj, H1v, ba, H0);
        k_stats256<<<144, 256, 0, stream>>>(H0, st1);
        k_finalize<<<1, H1D, 0, stream>>>(st1, ga, bta, coef1, H1D);
        k_gemm2<<<dim3(288, 1), 256, 0, stream>>>(H0, coef1, W0b, W1b, G0, G1v);
        k_combine2<<<BSZ, 256, 0, stream>>>(Adj, G1v, bb, G0);
        k_stats64<<<144, 256, 0, stream>>>(G0, st2);
        k_finalize<<<1, H2D, 0, stream>>>(st2, gb, btb, coef2, H2D);
        k_pool<<<BSZ, 64, 0, stream>>>(G0, coef2, feat);
    };

    branch(xF, eiF, TembF, SembF, W0F1, W1F1, bF1, gF1, btF1,
           W0F2, W1F2, bF2, gF2, btF2, featF);
    branch(xD, eiD, TembD, SembD, W0D1, W1D1, bD1, gD1, btD1,
           W0D2, W1D2, bD2, gD2, btD2, featD);

    k_heads<<<BSZ, 128, 0, stream>>>(featF, featD, WlinF, blinF, WlinD, blinD,
                                     Wlin, blin, (float*)d_out);
}

// Round 2
// 995.715 us; speedup vs baseline: 2.7316x; 2.7316x over previous
//
#include <hip/hip_runtime.h>
#include <math.h>

// ---------------- problem constants ----------------
#define NN    36864        // N = B*V
#define F0    1025
#define H1D   256
#define H2D   64
#define VV    36
#define SS    12
#define BSZ   1024         // N / V
#define BN_EPS 1e-5f

typedef __bf16 bf16x8 __attribute__((ext_vector_type(8)));
typedef float  f32x4  __attribute__((ext_vector_type(4)));

// ---------------- utility ----------------
__global__ void k_zero(float* __restrict__ p, int n) {
    int i = blockIdx.x * blockDim.x + threadIdx.x;
    if (i < n) p[i] = 0.f;
}

__global__ void k_deg(const int* __restrict__ src, int E, float* __restrict__ deg) {
    int e = blockIdx.x * blockDim.x + threadIdx.x;
    if (e < E) atomicAdd(&deg[src[e]], 1.f);
}

__device__ __forceinline__ float dinv_f(float d) {
    return d > 0.f ? rsqrtf(fmaxf(d, 1.f)) : 0.f;
}

__global__ void k_scatter(const int* __restrict__ src, const int* __restrict__ dst, int E,
                          const float* __restrict__ deg, float* __restrict__ Adj) {
    int e = blockIdx.x * blockDim.x + threadIdx.x;
    if (e >= E) return;
    int s = src[e], d = dst[e];
    float w = -dinv_f(deg[s]) * dinv_f(deg[d]);
    int blk = s / VV;
    atomicAdd(&Adj[(size_t)blk * (VV * VV) + (d - blk * VV) * VV + (s - blk * VV)], w);
}

// ---------------- prep A: bf16 tiled+swizzled [bm][kt=17][128r x 64k] ----------------
// element (r,k) of tile -> tile_off r*64 + ((g ^ (r&7))*8 + k%8), g = (k%64)/8
__global__ __launch_bounds__(256) void k_prepA(
    const float* __restrict__ x, const float* __restrict__ Temb, const float* __restrict__ Semb,
    __bf16* __restrict__ Abf, int row0) {
    int id = blockIdx.x * 256 + threadIdx.x;     // 9216 rows * 136 granules
    int lr = id / 136, gi = id - lr * 136;
    int gr = row0 + lr;
    int kt = gi >> 3, g = gi & 7;
    int k0 = kt * 64 + g * 8;
    int lv = gr % VV;
    const float* px = x + (size_t)gr * F0;
    const float* pt = Temb + (size_t)(lv / SS) * F0;
    const float* ps = Semb + (size_t)(lv % SS) * F0;
    bf16x8 ov;
#pragma unroll
    for (int j = 0; j < 8; ++j) {
        int k = k0 + j;
        float v = (k < F0) ? (px[k] + pt[k] + ps[k]) : 0.f;
        ov[j] = (__bf16)v;
    }
    int r = lr & 127, bmq = lr >> 7;
    size_t dst = ((size_t)(bmq * 17 + kt) << 13) + r * 64 + ((g ^ (r & 7)) << 3);
    *(bf16x8*)(Abf + dst) = ov;
}

// ---------------- prep W: [bn][kt][128c x 64k] tiled+swizzled, cols = Wa|Wb ----------------
__global__ __launch_bounds__(256) void k_prepW(
    const float* __restrict__ Wa, const float* __restrict__ Wb,
    __bf16* __restrict__ Wt, int K, int nkt, int split, int ldw) {
    int id = blockIdx.x * 256 + threadIdx.x;
    int gpc = nkt * 8;
    int c = id / gpc, gi = id - c * gpc;
    int kt = gi >> 3, g = gi & 7;
    int k0 = kt * 64 + g * 8;
    const float* src = (c < split) ? (Wa + c) : (Wb + (c - split));
    bf16x8 ov;
#pragma unroll
    for (int j = 0; j < 8; ++j) {
        int k = k0 + j;
        float v = (k < K) ? src[(size_t)k * ldw] : 0.f;
        ov[j] = (__bf16)v;
    }
    int r = c & 127, bn = c >> 7;
    size_t dst = ((size_t)(bn * nkt + kt) << 13) + r * 64 + ((g ^ (r & 7)) << 3);
    *(bf16x8*)(Wt + dst) = ov;
}

// ---------------- prep Y (GEMM2 A): bf16(relu(Y*sA+sB)) tiled+swizzled ----------------
__global__ __launch_bounds__(256) void k_prepY(
    const float* __restrict__ Y, const float* __restrict__ coef, __bf16* __restrict__ Ybf) {
    int id = blockIdx.x * 256 + threadIdx.x;     // 36864 rows * 32 granules
    int lr = id >> 5, gi = id & 31;
    int kt = gi >> 3, g = gi & 7;
    int k0 = kt * 64 + g * 8;
    const float* py = Y + (size_t)lr * H1D + k0;
    bf16x8 ov;
#pragma unroll
    for (int j = 0; j < 8; ++j) {
        int k = k0 + j;
        float v = fmaxf(fmaf(py[j], coef[k], coef[H1D + k]), 0.f);
        ov[j] = (__bf16)v;
    }
    int r = lr & 127, bm = lr >> 7;
    size_t dst = ((size_t)(bm * 4 + kt) << 13) + r * 64 + ((g ^ (r & 7)) << 3);
    *(bf16x8*)(Ybf + dst) = ov;
}

// ---------------- MFMA GEMM: C[128x128 per block] = At @ Bt^T ----------------
// At: [gridx][KT] 16KB tiles (rows), Bt: [gridy][KT] tiles (cols). 4 waves 2x2, 64x64/wave.
__global__ __launch_bounds__(256) void k_mfma_gemm(
    const __bf16* __restrict__ At, const __bf16* __restrict__ Bt,
    float* __restrict__ outA, __bf16* __restrict__ outB,
    int KT, int split, int ldc, int row0) {
    __shared__ __align__(16) __bf16 As[8192];
    __shared__ __align__(16) __bf16 Bs[8192];
    const int tid = threadIdx.x;
    const int lane = tid & 63, wid = tid >> 6;
    const int bm = blockIdx.x, bn = blockIdx.y;
    const int wr = wid >> 1, wc = wid & 1;
    const int l15 = lane & 15, lg = lane >> 4;

    f32x4 acc[4][4];
#pragma unroll
    for (int m = 0; m < 4; ++m)
#pragma unroll
        for (int n = 0; n < 4; ++n) acc[m][n] = (f32x4){0.f, 0.f, 0.f, 0.f};

    // fragment LDS element offsets (swizzled): k-granule (kk*4+lg) XOR (row&7)
    int offA[2][4], offB[2][4];
#pragma unroll
    for (int kk = 0; kk < 2; ++kk)
#pragma unroll
        for (int m = 0; m < 4; ++m) {
            int rowA = wr * 64 + m * 16 + l15;
            offA[kk][m] = rowA * 64 + (((kk * 4 + lg) ^ (rowA & 7)) << 3);
            int rowB = wc * 64 + m * 16 + l15;
            offB[kk][m] = rowB * 64 + (((kk * 4 + lg) ^ (rowB & 7)) << 3);
        }

    const __bf16* pA = At + ((size_t)bm * KT << 13) + (lane << 3);
    const __bf16* pB = Bt + ((size_t)bn * KT << 13) + (lane << 3);

    for (int kt = 0; kt < KT; ++kt) {
        const __bf16* sA = pA + ((size_t)kt << 13);
        const __bf16* sB = pB + ((size_t)kt << 13);
#pragma unroll
        for (int c = 0; c < 4; ++c) {
            int q = (wid * 4 + c) * 512;   // 1KB chunk per wave-instruction
            __builtin_amdgcn_global_load_lds(
                (const __attribute__((address_space(1))) void*)(sA + q),
                (__attribute__((address_space(3))) void*)(As + q), 16, 0, 0);
            __builtin_amdgcn_global_load_lds(
                (const __attribute__((address_space(1))) void*)(sB + q),
                (__attribute__((address_space(3))) void*)(Bs + q), 16, 0, 0);
        }
        __syncthreads();
#pragma unroll
        for (int kk = 0; kk < 2; ++kk) {
            bf16x8 af[4], bb[4];
#pragma unroll
            for (int m = 0; m < 4; ++m) af[m] = *(const bf16x8*)(&As[offA[kk][m]]);
#pragma unroll
            for (int n = 0; n < 4; ++n) bb[n] = *(const bf16x8*)(&Bs[offB[kk][n]]);
#pragma unroll
            for (int m = 0; m < 4; ++m)
#pragma unroll
                for (int n = 0; n < 4; ++n)
                    acc[m][n] = __builtin_amdgcn_mfma_f32_16x16x32_bf16(
                        af[m], bb[n], acc[m][n], 0, 0, 0);
        }
        __syncthreads();
    }

    // epilogue: C row = (lane>>4)*4+j, col = lane&15 within each 16x16 fragment
    const int cr = lg * 4, cc = l15;
#pragma unroll
    for (int m = 0; m < 4; ++m) {
        int grow = row0 + bm * 128 + wr * 64 + m * 16 + cr;
#pragma unroll
        for (int n = 0; n < 4; ++n) {
            int col = bn * 128 + wc * 64 + n * 16 + cc;
#pragma unroll
            for (int j = 0; j < 4; ++j) {
                int r = grow + j;
                if (col < split) outA[(size_t)r * ldc + col] = acc[m][n][j];
                else             outB[(size_t)r * ldc + (col - split)] = (__bf16)acc[m][n][j];
            }
        }
    }
}

// ---------------- cheb combine layer1: Y = H0 + Adj @ H1 + b (in-place) ----------------
__global__ __launch_bounds__(256) void k_combine1(
    const float* __restrict__ Adj, const __bf16* __restrict__ H1v,
    const float* __restrict__ bias, float* __restrict__ Y) {
    __shared__ float Adj_s[VV * VV];
    __shared__ float H1_s[VV * H1D];
    int b = blockIdx.x, t = threadIdx.x;
    for (int e = t; e < VV * VV; e += 256) Adj_s[e] = Adj[(size_t)b * VV * VV + e];
    const __bf16* h1b = H1v + (size_t)b * VV * H1D;
    for (int e = t; e < VV * H1D; e += 256) H1_s[e] = (float)h1b[e];
    __syncthreads();
    float bv = bias[t];
    float* yb = Y + (size_t)b * VV * H1D;
    for (int r = 0; r < VV; ++r) {
        float acc = yb[r * H1D + t] + bv;
#pragma unroll
        for (int j = 0; j < VV; ++j) acc += Adj_s[r * VV + j] * H1_s[j * H1D + t];
        yb[r * H1D + t] = acc;
    }
}

// ---------------- BN stats ----------------
__global__ __launch_bounds__(256) void k_stats256(const float* __restrict__ Y, float* __restrict__ st) {
    int t = threadIdx.x;
    int r0 = blockIdx.x * 256;
    float s = 0.f, s2 = 0.f;
    for (int i = 0; i < 256; ++i) {
        float v = Y[(size_t)(r0 + i) * H1D + t];
        s += v; s2 += v * v;
    }
    atomicAdd(&st[t], s);
    atomicAdd(&st[H1D + t], s2);
}

__global__ __launch_bounds__(256) void k_stats64(const float* __restrict__ Y, float* __restrict__ st) {
    int t = threadIdx.x;
    int c = t & 63, rg = t >> 6;
    int r0 = blockIdx.x * 256;
    float s = 0.f, s2 = 0.f;
    for (int i = 0; i < 64; ++i) {
        float v = Y[(size_t)(r0 + rg + 4 * i) * H2D + c];
        s += v; s2 += v * v;
    }
    atomicAdd(&st[c], s);
    atomicAdd(&st[H2D + c], s2);
}

__global__ void k_finalize(const float* __restrict__ st, const float* __restrict__ g,
                           const float* __restrict__ bt, float* __restrict__ coef, int H) {
    int t = threadIdx.x;
    if (t >= H) return;
    float mu = st[t] / (float)NN;
    float var = st[H + t] / (float)NN - mu * mu;
    float sA = g[t] * rsqrtf(var + BN_EPS);
    coef[t] = sA;
    coef[H + t] = bt[t] - mu * sA;
}

// ---------------- cheb combine layer2 (in-place into G0) ----------------
__global__ __launch_bounds__(256) void k_combine2(
    const float* __restrict__ Adj, const __bf16* __restrict__ G1v,
    const float* __restrict__ bias, float* __restrict__ Y2) {
    __shared__ float Adj_s[VV * VV];
    __shared__ float G1_s[VV * H2D];
    int b = blockIdx.x, t = threadIdx.x;
    for (int e = t; e < VV * VV; e += 256) Adj_s[e] = Adj[(size_t)b * VV * VV + e];
    const __bf16* g1b = G1v + (size_t)b * VV * H2D;
    for (int e = t; e < VV * H2D; e += 256) G1_s[e] = (float)g1b[e];
    __syncthreads();
    int c = t & 63, rg = t >> 6;
    float bv = bias[c];
    float* yb = Y2 + (size_t)b * VV * H2D;
    for (int r = rg; r < VV; r += 4) {
        float acc = yb[r * H2D + c] + bv;
#pragma unroll
        for (int j = 0; j < VV; ++j) acc += Adj_s[r * VV + j] * G1_s[j * H2D + c];
        yb[r * H2D + c] = acc;
    }
}

// ---------------- pool ----------------
__global__ __launch_bounds__(64) void k_pool(const float* __restrict__ Y2,
                                             const float* __restrict__ coef,
                                             float* __restrict__ feat) {
    int b = blockIdx.x, c = threadIdx.x;
    float sA = coef[c], sB = coef[H2D + c];
    float mx = -1e30f, sm = 0.f;
    const float* yb = Y2 + ((size_t)b * VV + SS) * H2D + c;
#pragma unroll
    for (int i = 0; i < SS; ++i) {
        float v = fmaxf(fmaf(yb[i * H2D], sA, sB), 0.f);
        mx = fmaxf(mx, v);
        sm += v;
    }
    feat[b * 128 + c] = mx;
    feat[b * 128 + 64 + c] = sm * (1.f / 12.f);
}

// ---------------- heads ----------------
__global__ __launch_bounds__(128) void k_heads(
    const float* __restrict__ featF, const float* __restrict__ featD,
    const float* __restrict__ WlinF, const float* __restrict__ blinF,
    const float* __restrict__ WlinD, const float* __restrict__ blinD,
    const float* __restrict__ Wlin, const float* __restrict__ blin,
    float* __restrict__ out) {
    __shared__ float sF[128], sD[128], lg[24];
    int r = blockIdx.x, t = threadIdx.x;
    sF[t] = featF[r * 128 + t];
    sD[t] = featD[r * 128 + t];
    __syncthreads();
    float* fus = out + 10240 + (size_t)r * 256;
    fus[t] = sF[t];
    fus[128 + t] = sD[t];
    if (t < 5) {
        float a = blinF[t];
        for (int k = 0; k < 128; ++k) a += sF[k] * WlinF[k * 5 + t];
        lg[t] = a;
    } else if (t >= 8 && t < 13) {
        int j = t - 8;
        float a = blinD[j];
        for (int k = 0; k < 128; ++k) a += sD[k] * WlinD[k * 5 + j];
        lg[8 + j] = a;
    } else if (t >= 16 && t < 21) {
        int j = t - 16;
        float a = blin[j];
        for (int k = 0; k < 128; ++k) a += sF[k] * Wlin[k * 5 + j];
        for (int k = 0; k < 128; ++k) a += sD[k] * Wlin[(128 + k) * 5 + j];
        lg[16 + j] = a;
    }
    __syncthreads();
    if (t < 15) {
        int grp = t / 5, j = t % 5;
        const float* l = &lg[grp * 8];
        float m = l[0];
#pragma unroll
        for (int k = 1; k < 5; ++k) m = fmaxf(m, l[k]);
        float den = 0.f;
#pragma unroll
        for (int k = 0; k < 5; ++k) den += expf(l[k] - m);
        float v = expf(l[j] - m) / den;
        float* dst = (grp == 0) ? out : (grp == 1 ? out + 5120 : out + 272384);
        dst[r * 5 + j] = v;
    }
}

// ---------------- launch ----------------
extern "C" void kernel_launch(void* const* d_in, const int* in_sizes, int n_in,
                              void* d_out, int out_size, void* d_ws, size_t ws_size,
                              hipStream_t stream) {
    const float* xF    = (const float*)d_in[0];
    const float* xD    = (const float*)d_in[1];
    const int*   eiF   = (const int*)d_in[2];
    const int*   eiD   = (const int*)d_in[3];
    const float* TembF = (const float*)d_in[4];
    const float* SembF = (const float*)d_in[5];
    const float* TembD = (const float*)d_in[6];
    const float* SembD = (const float*)d_in[7];
    const float* W0F1  = (const float*)d_in[8];
    const float* W1F1  = (const float*)d_in[9];
    const float* bF1   = (const float*)d_in[10];
    const float* gF1   = (const float*)d_in[11];
    const float* btF1  = (const float*)d_in[12];
    const float* W0F2  = (const float*)d_in[13];
    const float* W1F2  = (const float*)d_in[14];
    const float* bF2   = (const float*)d_in[15];
    const float* gF2   = (const float*)d_in[16];
    const float* btF2  = (const float*)d_in[17];
    const float* W0D1  = (const float*)d_in[18];
    const float* W1D1  = (const float*)d_in[19];
    const float* bD1   = (const float*)d_in[20];
    const float* gD1   = (const float*)d_in[21];
    const float* btD1  = (const float*)d_in[22];
    const float* W0D2  = (const float*)d_in[23];
    const float* W1D2  = (const float*)d_in[24];
    const float* bD2   = (const float*)d_in[25];
    const float* gD2   = (const float*)d_in[26];
    const float* btD2  = (const float*)d_in[27];
    const float* WlinF = (const float*)d_in[28];
    const float* blinF = (const float*)d_in[29];
    const float* WlinD = (const float*)d_in[30];
    const float* blinD = (const float*)d_in[31];
    const float* Wlin  = (const float*)d_in[32];
    const float* blin  = (const float*)d_in[33];

    const int E = in_sizes[2] / 2;

    // -------- workspace layout (float units) --------
    float* ws = (float*)d_ws;
    size_t o = 0;
    float*  H0   = ws + o;              o += (size_t)NN * H1D;        // 37.75 MB fp32
    __bf16* H1bf = (__bf16*)(ws + o);   o += (size_t)NN * H1D / 2;    // 18.9 MB bf16
    __bf16* Abf  = (__bf16*)(ws + o);   o += (size_t)72 * 17 * 8192 / 2; // 20 MB (reused as Ybf)
    float*  G0   = ws + o;              o += (size_t)NN * H2D;        // 9.4 MB
    __bf16* G1bf = (__bf16*)(ws + o);   o += (size_t)NN * H2D / 2;    // 4.7 MB
    __bf16* Wt1  = (__bf16*)(ws + o);   o += (size_t)4 * 17 * 8192 / 2;
    __bf16* Wt2  = (__bf16*)(ws + o);   o += (size_t)4 * 8192 / 2;
    float*  Adj  = ws + o;              o += (size_t)BSZ * VV * VV;   // zero span start
    float*  deg  = ws + o;              o += NN;
    float*  st1  = ws + o;              o += 2 * H1D;
    float*  st2  = ws + o;              o += 2 * H2D;                 // zero span end
    float*  coef1 = ws + o;             o += 2 * H1D;
    float*  coef2 = ws + o;             o += 2 * H2D;
    float*  featF = ws + o;             o += (size_t)BSZ * 128;
    float*  featD = ws + o;             o += (size_t)BSZ * 128;

    const int zeroN = BSZ * VV * VV + NN + 2 * H1D + 2 * H2D;

    auto branch = [&](const float* x, const int* ei,
                      const float* Temb, const float* Semb,
                      const float* W0a, const float* W1a, const float* ba,
                      const float* ga, const float* bta,
                      const float* W0b, const float* W1b, const float* bb,
                      const float* gb, const float* btb, float* feat) {
        k_zero<<<(zeroN + 255) / 256, 256, 0, stream>>>(Adj, zeroN);
        k_deg<<<(E + 255) / 256, 256, 0, stream>>>(ei, E, deg);
        k_scatter<<<(E + 255) / 256, 256, 0, stream>>>(ei, ei + E, E, deg, Adj);
        k_prepW<<<272, 256, 0, stream>>>(W0a, W1a, Wt1, F0, 17, 256, H1D);
        k_prepW<<<16, 256, 0, stream>>>(W0b, W1b, Wt2, H1D, 4, 64, H2D);
        for (int q = 0; q < 4; ++q) {
            k_prepA<<<4896, 256, 0, stream>>>(x, Temb, Semb, Abf, q * 9216);
            k_mfma_gemm<<<dim3(72, 4), 256, 0, stream>>>(Abf, Wt1, H0, H1bf,
                                                         17, 256, H1D, q * 9216);
        }
        k_combine1<<<BSZ, 256, 0, stream>>>(Adj, H1bf, ba, H0);
        k_stats256<<<144, 256, 0, stream>>>(H0, st1);
        k_finalize<<<1, H1D, 0, stream>>>(st1, ga, bta, coef1, H1D);
        k_prepY<<<4608, 256, 0, stream>>>(H0, coef1, Abf);   // Ybf aliases Abf
        k_mfma_gemm<<<dim3(288, 1), 256, 0, stream>>>(Abf, Wt2, G0, G1bf,
                                                      4, 64, H2D, 0);
        k_combine2<<<BSZ, 256, 0, stream>>>(Adj, G1bf, bb, G0);
        k_stats64<<<144, 256, 0, stream>>>(G0, st2);
        k_finalize<<<1, H2D, 0, stream>>>(st2, gb, btb, coef2, H2D);
        k_pool<<<BSZ, 64, 0, stream>>>(G0, coef2, feat);
    };

    branch(xF, eiF, TembF, SembF, W0F1, W1F1, bF1, gF1, btF1,
           W0F2, W1F2, bF2, gF2, btF2, featF);
    branch(xD, eiD, TembD, SembD, W0D1, W1D1, bD1, gD1, btD1,
           W0D2, W1D2, bD2, gD2, btD2, featD);

    k_heads<<<BSZ, 128, 0, stream>>>(featF, featD, WlinF, blinF, WlinD, blinD,
                                     Wlin, blin, (float*)d_out);
}

// Round 3
// 853.939 us; speedup vs baseline: 3.1851x; 1.1660x over previous
//
#include <hip/hip_runtime.h>
#include <math.h>

// ---------------- problem constants ----------------
#define NN    36864        // N = B*V
#define F0    1025
#define H1D   256
#define H2D   64
#define VV    36
#define SS    12
#define BSZ   1024         // N / V
#define BN_EPS 1e-5f

#define KT1   17                       // ceil(1025/64)
#define ABR_STRIDE  ((size_t)288*17*8192)   // bf16 elems per branch (A tiles)
#define WT1_STRIDE  ((size_t)4*17*8192)
#define YBF_STRIDE  ((size_t)288*4*8192)
#define WT2_STRIDE  ((size_t)4*8192)

typedef __bf16 bf16x8 __attribute__((ext_vector_type(8)));
typedef __bf16 bf16x4 __attribute__((ext_vector_type(4)));
typedef float  f32x4  __attribute__((ext_vector_type(4)));

// ---------------- utility ----------------
__global__ void k_zero(float* __restrict__ p, int n) {
    int i = blockIdx.x * blockDim.x + threadIdx.x;
    if (i < n) p[i] = 0.f;
}

__global__ void k_deg(const int* __restrict__ eiF, const int* __restrict__ eiD,
                      int E, float* __restrict__ degAll) {
    int br = blockIdx.y;
    const int* src = br ? eiD : eiF;
    float* deg = degAll + (size_t)br * NN;
    int e = blockIdx.x * blockDim.x + threadIdx.x;
    if (e < E) atomicAdd(&deg[src[e]], 1.f);
}

__device__ __forceinline__ float dinv_f(float d) {
    return d > 0.f ? rsqrtf(fmaxf(d, 1.f)) : 0.f;
}

__global__ void k_scatter(const int* __restrict__ eiF, const int* __restrict__ eiD,
                          int E, const float* __restrict__ degAll, float* __restrict__ AdjAll) {
    int br = blockIdx.y;
    const int* src = br ? eiD : eiF;
    const int* dst = src + E;
    const float* deg = degAll + (size_t)br * NN;
    float* Adj = AdjAll + (size_t)br * BSZ * (VV * VV);
    int e = blockIdx.x * blockDim.x + threadIdx.x;
    if (e >= E) return;
    int s = src[e], d = dst[e];
    float w = -dinv_f(deg[s]) * dinv_f(deg[d]);
    int blk = s / VV;
    atomicAdd(&Adj[(size_t)blk * (VV * VV) + (d - blk * VV) * VV + (s - blk * VV)], w);
}

// ---------------- prep A: bf16 tiled+swizzled [bm][kt][128r x 64k], full M, both branches ----
__global__ __launch_bounds__(256) void k_prepA(
    const float* __restrict__ xF, const float* __restrict__ xD,
    const float* __restrict__ TembF, const float* __restrict__ SembF,
    const float* __restrict__ TembD, const float* __restrict__ SembD,
    __bf16* __restrict__ Abf) {
    int br = blockIdx.y;
    const float* x    = br ? xD : xF;
    const float* Temb = br ? TembD : TembF;
    const float* Semb = br ? SembD : SembF;
    __bf16* out = Abf + (size_t)br * ABR_STRIDE;

    int id = blockIdx.x * 256 + threadIdx.x;   // 36864 rows * 136 granules
    int lr = id / 136, gi = id - lr * 136;
    int kt = gi >> 3, g = gi & 7;
    int k0 = kt * 64 + g * 8;
    int lv = lr % VV;
    const float* px = x + (size_t)lr * F0;
    const float* pt = Temb + (size_t)(lv / SS) * F0;
    const float* ps = Semb + (size_t)(lv % SS) * F0;
    bf16x8 ov;
#pragma unroll
    for (int j = 0; j < 8; ++j) {
        int k = k0 + j;
        float v = (k < F0) ? (px[k] + pt[k] + ps[k]) : 0.f;
        ov[j] = (__bf16)v;
    }
    int r = lr & 127, bm = lr >> 7;
    size_t dst = ((size_t)(bm * KT1 + kt) << 13) + r * 64 + ((g ^ (r & 7)) << 3);
    *(bf16x8*)(out + dst) = ov;
}

// ---------------- prep W: [bn][kt][128c x 64k] tiled+swizzled, both branches ----------------
__global__ __launch_bounds__(256) void k_prepW(
    const float* __restrict__ WaF, const float* __restrict__ WbF,
    const float* __restrict__ WaD, const float* __restrict__ WbD,
    __bf16* __restrict__ Wt, int K, int nkt, int split, int ldw, size_t brStride) {
    int br = blockIdx.y;
    const float* Wa = br ? WaD : WaF;
    const float* Wb = br ? WbD : WbF;
    __bf16* out = Wt + (size_t)br * brStride;

    int id = blockIdx.x * 256 + threadIdx.x;
    int gpc = nkt * 8;
    int c = id / gpc, gi = id - c * gpc;
    int kt = gi >> 3, g = gi & 7;
    int k0 = kt * 64 + g * 8;
    const float* src = (c < split) ? (Wa + c) : (Wb + (c - split));
    bf16x8 ov;
#pragma unroll
    for (int j = 0; j < 8; ++j) {
        int k = k0 + j;
        float v = (k < K) ? src[(size_t)k * ldw] : 0.f;
        ov[j] = (__bf16)v;
    }
    int r = c & 127, bn = c >> 7;
    size_t dst = ((size_t)(bn * nkt + kt) << 13) + r * 64 + ((g ^ (r & 7)) << 3);
    *(bf16x8*)(out + dst) = ov;
}

// ---------------- prep Y (GEMM2 A): bf16(relu(Y*sA+sB)) tiled+swizzled, both branches -------
__global__ __launch_bounds__(256) void k_prepY(
    const float* __restrict__ YAll, const float* __restrict__ coefAll,
    __bf16* __restrict__ YbfAll) {
    int br = blockIdx.y;
    const float* Y = YAll + (size_t)br * NN * H1D;
    const float* coef = coefAll + (size_t)br * 2 * H1D;
    __bf16* out = YbfAll + (size_t)br * YBF_STRIDE;

    int id = blockIdx.x * 256 + threadIdx.x;   // 36864 rows * 32 granules
    int lr = id >> 5, gi = id & 31;
    int kt = gi >> 3, g = gi & 7;
    int k0 = kt * 64 + g * 8;
    const float* py = Y + (size_t)lr * H1D + k0;
    bf16x8 ov;
#pragma unroll
    for (int j = 0; j < 8; ++j) {
        int k = k0 + j;
        float v = fmaxf(fmaf(py[j], coef[k], coef[H1D + k]), 0.f);
        ov[j] = (__bf16)v;
    }
    int r = lr & 127, bm = lr >> 7;
    size_t dst = ((size_t)(bm * 4 + kt) << 13) + r * 64 + ((g ^ (r & 7)) << 3);
    *(bf16x8*)(out + dst) = ov;
}

// ---------------- MFMA GEMM: C[128x128 per block] = At @ Bt^T, z = branch ----------------
__global__ __launch_bounds__(256) void k_mfma_gemm(
    const __bf16* __restrict__ AtAll, const __bf16* __restrict__ BtAll,
    float* __restrict__ outAAll, __bf16* __restrict__ outBAll,
    int KT, int split, int ldc,
    size_t strideAt, size_t strideBt, size_t strideOutA, size_t strideOutB) {
    __shared__ __align__(16) __bf16 As[8192];
    __shared__ __align__(16) __bf16 Bs[8192];
    const int tid = threadIdx.x;
    const int lane = tid & 63, wid = tid >> 6;
    const int bm = blockIdx.x, bn = blockIdx.y, br = blockIdx.z;
    const int wr = wid >> 1, wc = wid & 1;
    const int l15 = lane & 15, lg = lane >> 4;

    const __bf16* At = AtAll + (size_t)br * strideAt;
    const __bf16* Bt = BtAll + (size_t)br * strideBt;
    float*  outA = outAAll + (size_t)br * strideOutA;
    __bf16* outB = outBAll + (size_t)br * strideOutB;

    f32x4 acc[4][4];
#pragma unroll
    for (int m = 0; m < 4; ++m)
#pragma unroll
        for (int n = 0; n < 4; ++n) acc[m][n] = (f32x4){0.f, 0.f, 0.f, 0.f};

    int offA[2][4], offB[2][4];
#pragma unroll
    for (int kk = 0; kk < 2; ++kk)
#pragma unroll
        for (int m = 0; m < 4; ++m) {
            int rowA = wr * 64 + m * 16 + l15;
            offA[kk][m] = rowA * 64 + (((kk * 4 + lg) ^ (rowA & 7)) << 3);
            int rowB = wc * 64 + m * 16 + l15;
            offB[kk][m] = rowB * 64 + (((kk * 4 + lg) ^ (rowB & 7)) << 3);
        }

    const __bf16* pA = At + ((size_t)bm * KT << 13) + (lane << 3);
    const __bf16* pB = Bt + ((size_t)bn * KT << 13) + (lane << 3);

    for (int kt = 0; kt < KT; ++kt) {
        const __bf16* sA = pA + ((size_t)kt << 13);
        const __bf16* sB = pB + ((size_t)kt << 13);
#pragma unroll
        for (int c = 0; c < 4; ++c) {
            int q = (wid * 4 + c) * 512;
            __builtin_amdgcn_global_load_lds(
                (const __attribute__((address_space(1))) void*)(sA + q),
                (__attribute__((address_space(3))) void*)(As + q), 16, 0, 0);
            __builtin_amdgcn_global_load_lds(
                (const __attribute__((address_space(1))) void*)(sB + q),
                (__attribute__((address_space(3))) void*)(Bs + q), 16, 0, 0);
        }
        __syncthreads();
#pragma unroll
        for (int kk = 0; kk < 2; ++kk) {
            bf16x8 af[4], bb[4];
#pragma unroll
            for (int m = 0; m < 4; ++m) af[m] = *(const bf16x8*)(&As[offA[kk][m]]);
#pragma unroll
            for (int n = 0; n < 4; ++n) bb[n] = *(const bf16x8*)(&Bs[offB[kk][n]]);
#pragma unroll
            for (int m = 0; m < 4; ++m)
#pragma unroll
                for (int n = 0; n < 4; ++n)
                    acc[m][n] = __builtin_amdgcn_mfma_f32_16x16x32_bf16(
                        af[m], bb[n], acc[m][n], 0, 0, 0);
        }
        __syncthreads();
    }

    const int cr = lg * 4, cc = l15;
#pragma unroll
    for (int m = 0; m < 4; ++m) {
        int grow = bm * 128 + wr * 64 + m * 16 + cr;
#pragma unroll
        for (int n = 0; n < 4; ++n) {
            int col = bn * 128 + wc * 64 + n * 16 + cc;
#pragma unroll
            for (int j = 0; j < 4; ++j) {
                int r = grow + j;
                if (col < split) outA[(size_t)r * ldc + col] = acc[m][n][j];
                else             outB[(size_t)r * ldc + (col - split)] = (__bf16)acc[m][n][j];
            }
        }
    }
}

// ---------------- combine1 + BN stats: Y = H0 + Adj@H1 + b; accumulate col sums ----------------
__global__ __launch_bounds__(256) void k_combine_stats1(
    const float* __restrict__ AdjAll, const __bf16* __restrict__ H1All,
    const float* __restrict__ bF, const float* __restrict__ bD,
    float* __restrict__ YAll, float* __restrict__ stAll) {
    __shared__ float Adj_s[VV * VV];
    __shared__ float red[256 * 9];
    int b = blockIdx.x, br = blockIdx.y, t = threadIdx.x;
    const float* Adj = AdjAll + ((size_t)br * BSZ + b) * (VV * VV);
    const __bf16* h1 = H1All + ((size_t)br * NN + (size_t)b * VV) * H1D;
    float* yb = YAll + ((size_t)br * NN + (size_t)b * VV) * H1D;
    float* st = stAll + (size_t)br * 2 * H1D;
    const float* bias = br ? bD : bF;

    for (int e = t; e < VV * VV; e += 256) Adj_s[e] = Adj[e];
    __syncthreads();

    int c0 = (t & 63) * 4, r0 = t >> 6;
    float4 bv = *reinterpret_cast<const float4*>(bias + c0);
    float acc[9][4];
#pragma unroll
    for (int i = 0; i < 9; ++i) {
        float4 y = *reinterpret_cast<const float4*>(yb + (size_t)(r0 + 4 * i) * H1D + c0);
        acc[i][0] = y.x + bv.x; acc[i][1] = y.y + bv.y;
        acc[i][2] = y.z + bv.z; acc[i][3] = y.w + bv.w;
    }
#pragma unroll 4
    for (int j = 0; j < VV; ++j) {
        bf16x4 hv = *reinterpret_cast<const bf16x4*>(h1 + (size_t)j * H1D + c0);
        float h0 = (float)hv[0], h1f = (float)hv[1], h2 = (float)hv[2], h3 = (float)hv[3];
#pragma unroll
        for (int i = 0; i < 9; ++i) {
            float a = Adj_s[(r0 + 4 * i) * VV + j];
            acc[i][0] = fmaf(a, h0, acc[i][0]);
            acc[i][1] = fmaf(a, h1f, acc[i][1]);
            acc[i][2] = fmaf(a, h2, acc[i][2]);
            acc[i][3] = fmaf(a, h3, acc[i][3]);
        }
    }
    float s[4] = {0, 0, 0, 0}, s2[4] = {0, 0, 0, 0};
#pragma unroll
    for (int i = 0; i < 9; ++i) {
        *reinterpret_cast<float4*>(yb + (size_t)(r0 + 4 * i) * H1D + c0) =
            make_float4(acc[i][0], acc[i][1], acc[i][2], acc[i][3]);
#pragma unroll
        for (int k = 0; k < 4; ++k) { s[k] += acc[i][k]; s2[k] += acc[i][k] * acc[i][k]; }
    }
#pragma unroll
    for (int k = 0; k < 4; ++k) { red[t * 9 + k] = s[k]; red[t * 9 + 4 + k] = s2[k]; }
    __syncthreads();
    {
        int cg = t >> 2, k = t & 3;
        float ss = 0.f, ss2 = 0.f;
#pragma unroll
        for (int q = 0; q < 4; ++q) {
            ss  += red[(q * 64 + cg) * 9 + k];
            ss2 += red[(q * 64 + cg) * 9 + 4 + k];
        }
        atomicAdd(&st[t], ss);
        atomicAdd(&st[H1D + t], ss2);
    }
}

// ---------------- combine2 + BN stats ----------------
__global__ __launch_bounds__(256) void k_combine_stats2(
    const float* __restrict__ AdjAll, const __bf16* __restrict__ G1All,
    const float* __restrict__ bF, const float* __restrict__ bD,
    float* __restrict__ YAll, float* __restrict__ stAll) {
    __shared__ float Adj_s[VV * VV];
    __shared__ float red[256 * 9];
    int b = blockIdx.x, br = blockIdx.y, t = threadIdx.x;
    const float* Adj = AdjAll + ((size_t)br * BSZ + b) * (VV * VV);
    const __bf16* g1 = G1All + ((size_t)br * NN + (size_t)b * VV) * H2D;
    float* yb = YAll + ((size_t)br * NN + (size_t)b * VV) * H2D;
    float* st = stAll + (size_t)br * 2 * H2D;
    const float* bias = br ? bD : bF;

    for (int e = t; e < VV * VV; e += 256) Adj_s[e] = Adj[e];
    __syncthreads();

    int c0 = (t & 15) * 4, r0 = t >> 4;          // r0 in 0..15
    int nr = (r0 < 4) ? 3 : 2;                   // rows r0, r0+16, (r0+32)
    float4 bv = *reinterpret_cast<const float4*>(bias + c0);
    float acc[3][4];
    for (int i = 0; i < nr; ++i) {
        float4 y = *reinterpret_cast<const float4*>(yb + (size_t)(r0 + 16 * i) * H2D + c0);
        acc[i][0] = y.x + bv.x; acc[i][1] = y.y + bv.y;
        acc[i][2] = y.z + bv.z; acc[i][3] = y.w + bv.w;
    }
#pragma unroll 4
    for (int j = 0; j < VV; ++j) {
        bf16x4 hv = *reinterpret_cast<const bf16x4*>(g1 + (size_t)j * H2D + c0);
        float h0 = (float)hv[0], h1f = (float)hv[1], h2 = (float)hv[2], h3 = (float)hv[3];
        for (int i = 0; i < nr; ++i) {
            float a = Adj_s[(r0 + 16 * i) * VV + j];
            acc[i][0] = fmaf(a, h0, acc[i][0]);
            acc[i][1] = fmaf(a, h1f, acc[i][1]);
            acc[i][2] = fmaf(a, h2, acc[i][2]);
            acc[i][3] = fmaf(a, h3, acc[i][3]);
        }
    }
    float s[4] = {0, 0, 0, 0}, s2[4] = {0, 0, 0, 0};
    for (int i = 0; i < nr; ++i) {
        *reinterpret_cast<float4*>(yb + (size_t)(r0 + 16 * i) * H2D + c0) =
            make_float4(acc[i][0], acc[i][1], acc[i][2], acc[i][3]);
#pragma unroll
        for (int k = 0; k < 4; ++k) { s[k] += acc[i][k]; s2[k] += acc[i][k] * acc[i][k]; }
    }
#pragma unroll
    for (int k = 0; k < 4; ++k) { red[t * 9 + k] = s[k]; red[t * 9 + 4 + k] = s2[k]; }
    __syncthreads();
    if (t < 2 * H2D) {
        int cg = (t & 63) >> 2, k = t & 3, which = t >> 6;  // which: 0=sum,1=sumsq
        float ss = 0.f;
#pragma unroll
        for (int q = 0; q < 16; ++q) ss += red[(q * 16 + cg) * 9 + which * 4 + k];
        atomicAdd(&st[(t >> 6) * H2D + (t & 63)], ss);
    }
}

// ---------------- finalize BN coefficients (both branches) ----------------
__global__ void k_fin(const float* __restrict__ stAll,
                      const float* __restrict__ gF, const float* __restrict__ btF,
                      const float* __restrict__ gD, const float* __restrict__ btD,
                      float* __restrict__ coefAll, int H) {
    int br = blockIdx.x, t = threadIdx.x;
    const float* st = stAll + (size_t)br * 2 * H;
    float* coef = coefAll + (size_t)br * 2 * H;
    const float* g = br ? gD : gF;
    const float* bt = br ? btD : btF;
    if (t >= H) return;
    float mu = st[t] / (float)NN;
    float var = st[H + t] / (float)NN - mu * mu;
    float sA = g[t] * rsqrtf(var + BN_EPS);
    coef[t] = sA;
    coef[H + t] = bt[t] - mu * sA;
}

// ---------------- pool ----------------
__global__ __launch_bounds__(64) void k_pool(const float* __restrict__ Y2All,
                                             const float* __restrict__ coefAll,
                                             float* __restrict__ featF,
                                             float* __restrict__ featD) {
    int b = blockIdx.x, br = blockIdx.y, c = threadIdx.x;
    const float* Y2 = Y2All + (size_t)br * NN * H2D;
    const float* coef = coefAll + (size_t)br * 2 * H2D;
    float* feat = br ? featD : featF;
    float sA = coef[c], sB = coef[H2D + c];
    float mx = -1e30f, sm = 0.f;
    const float* yb = Y2 + ((size_t)b * VV + SS) * H2D + c;
#pragma unroll
    for (int i = 0; i < SS; ++i) {
        float v = fmaxf(fmaf(yb[i * H2D], sA, sB), 0.f);
        mx = fmaxf(mx, v);
        sm += v;
    }
    feat[b * 128 + c] = mx;
    feat[b * 128 + 64 + c] = sm * (1.f / 12.f);
}

// ---------------- heads ----------------
__global__ __launch_bounds__(128) void k_heads(
    const float* __restrict__ featF, const float* __restrict__ featD,
    const float* __restrict__ WlinF, const float* __restrict__ blinF,
    const float* __restrict__ WlinD, const float* __restrict__ blinD,
    const float* __restrict__ Wlin, const float* __restrict__ blin,
    float* __restrict__ out) {
    __shared__ float sF[128], sD[128], lg[24];
    int r = blockIdx.x, t = threadIdx.x;
    sF[t] = featF[r * 128 + t];
    sD[t] = featD[r * 128 + t];
    __syncthreads();
    float* fus = out + 10240 + (size_t)r * 256;
    fus[t] = sF[t];
    fus[128 + t] = sD[t];
    if (t < 5) {
        float a = blinF[t];
        for (int k = 0; k < 128; ++k) a += sF[k] * WlinF[k * 5 + t];
        lg[t] = a;
    } else if (t >= 8 && t < 13) {
        int j = t - 8;
        float a = blinD[j];
        for (int k = 0; k < 128; ++k) a += sD[k] * WlinD[k * 5 + j];
        lg[8 + j] = a;
    } else if (t >= 16 && t < 21) {
        int j = t - 16;
        float a = blin[j];
        for (int k = 0; k < 128; ++k) a += sF[k] * Wlin[k * 5 + j];
        for (int k = 0; k < 128; ++k) a += sD[k] * Wlin[(128 + k) * 5 + j];
        lg[16 + j] = a;
    }
    __syncthreads();
    if (t < 15) {
        int grp = t / 5, j = t % 5;
        const float* l = &lg[grp * 8];
        float m = l[0];
#pragma unroll
        for (int k = 1; k < 5; ++k) m = fmaxf(m, l[k]);
        float den = 0.f;
#pragma unroll
        for (int k = 0; k < 5; ++k) den += expf(l[k] - m);
        float v = expf(l[j] - m) / den;
        float* dst = (grp == 0) ? out : (grp == 1 ? out + 5120 : out + 272384);
        dst[r * 5 + j] = v;
    }
}

// ---------------- launch ----------------
extern "C" void kernel_launch(void* const* d_in, const int* in_sizes, int n_in,
                              void* d_out, int out_size, void* d_ws, size_t ws_size,
                              hipStream_t stream) {
    const float* xF    = (const float*)d_in[0];
    const float* xD    = (const float*)d_in[1];
    const int*   eiF   = (const int*)d_in[2];
    const int*   eiD   = (const int*)d_in[3];
    const float* TembF = (const float*)d_in[4];
    const float* SembF = (const float*)d_in[5];
    const float* TembD = (const float*)d_in[6];
    const float* SembD = (const float*)d_in[7];
    const float* W0F1  = (const float*)d_in[8];
    const float* W1F1  = (const float*)d_in[9];
    const float* bF1   = (const float*)d_in[10];
    const float* gF1   = (const float*)d_in[11];
    const float* btF1  = (const float*)d_in[12];
    const float* W0F2  = (const float*)d_in[13];
    const float* W1F2  = (const float*)d_in[14];
    const float* bF2   = (const float*)d_in[15];
    const float* gF2   = (const float*)d_in[16];
    const float* btF2  = (const float*)d_in[17];
    const float* W0D1  = (const float*)d_in[18];
    const float* W1D1  = (const float*)d_in[19];
    const float* bD1   = (const float*)d_in[20];
    const float* gD1   = (const float*)d_in[21];
    const float* btD1  = (const float*)d_in[22];
    const float* W0D2  = (const float*)d_in[23];
    const float* W1D2  = (const float*)d_in[24];
    const float* bD2   = (const float*)d_in[25];
    const float* gD2   = (const float*)d_in[26];
    const float* btD2  = (const float*)d_in[27];
    const float* WlinF = (const float*)d_in[28];
    const float* blinF = (const float*)d_in[29];
    const float* WlinD = (const float*)d_in[30];
    const float* blinD = (const float*)d_in[31];
    const float* Wlin  = (const float*)d_in[32];
    const float* blin  = (const float*)d_in[33];

    const int E = in_sizes[2] / 2;   // 589824 per branch

    // -------- workspace layout (float units); [2] = branch-major --------
    float* ws = (float*)d_ws;
    size_t o = 0;
    float*  H0   = ws + o;              o += (size_t)2 * NN * H1D;          // 75.5 MB
    __bf16* H1bf = (__bf16*)(ws + o);   o += (size_t)2 * NN * H1D / 2;      // 37.7 MB
    __bf16* Abf  = (__bf16*)(ws + o);   o += (size_t)2 * ABR_STRIDE / 2;    // 160 MB (Ybf aliases)
    float*  G0   = ws + o;              o += (size_t)2 * NN * H2D;          // 18.9 MB
    __bf16* G1bf = (__bf16*)(ws + o);   o += (size_t)2 * NN * H2D / 2;      // 9.4 MB
    __bf16* Wt1  = (__bf16*)(ws + o);   o += (size_t)2 * WT1_STRIDE / 2;
    __bf16* Wt2  = (__bf16*)(ws + o);   o += (size_t)2 * WT2_STRIDE / 2;
    float*  Adj  = ws + o;              o += (size_t)2 * BSZ * VV * VV;     // zero span start
    float*  deg  = ws + o;              o += (size_t)2 * NN;
    float*  st1  = ws + o;              o += 2 * 2 * H1D;
    float*  st2  = ws + o;              o += 2 * 2 * H2D;                   // zero span end
    float*  coef1 = ws + o;             o += 2 * 2 * H1D;
    float*  coef2 = ws + o;             o += 2 * 2 * H2D;
    float*  featF = ws + o;             o += (size_t)BSZ * 128;
    float*  featD = ws + o;             o += (size_t)BSZ * 128;

    const int zeroN = 2 * (BSZ * VV * VV + NN + 2 * H1D + 2 * H2D);

    k_zero<<<(zeroN + 255) / 256, 256, 0, stream>>>(Adj, zeroN);
    k_deg<<<dim3((E + 255) / 256, 2), 256, 0, stream>>>(eiF, eiD, E, deg);
    k_scatter<<<dim3((E + 255) / 256, 2), 256, 0, stream>>>(eiF, eiD, E, deg, Adj);
    k_prepW<<<dim3(272, 2), 256, 0, stream>>>(W0F1, W1F1, W0D1, W1D1, Wt1,
                                              F0, 17, 256, H1D, WT1_STRIDE);
    k_prepW<<<dim3(16, 2), 256, 0, stream>>>(W0F2, W1F2, W0D2, W1D2, Wt2,
                                             H1D, 4, 64, H2D, WT2_STRIDE);
    k_prepA<<<dim3(19584, 2), 256, 0, stream>>>(xF, xD, TembF, SembF, TembD, SembD, Abf);
    k_mfma_gemm<<<dim3(288, 4, 2), 256, 0, stream>>>(
        Abf, Wt1, H0, H1bf, KT1, 256, H1D,
        ABR_STRIDE, WT1_STRIDE, (size_t)NN * H1D, (size_t)NN * H1D);
    k_combine_stats1<<<dim3(BSZ, 2), 256, 0, stream>>>(Adj, H1bf, bF1, bD1, H0, st1);
    k_fin<<<dim3(2), 256, 0, stream>>>(st1, gF1, btF1, gD1, btD1, coef1, H1D);
    k_prepY<<<dim3(4608, 2), 256, 0, stream>>>(H0, coef1, Abf);
    k_mfma_gemm<<<dim3(288, 1, 2), 256, 0, stream>>>(
        Abf, Wt2, G0, G1bf, 4, 64, H2D,
        YBF_STRIDE, WT2_STRIDE, (size_t)NN * H2D, (size_t)NN * H2D);
    k_combine_stats2<<<dim3(BSZ, 2), 256, 0, stream>>>(Adj, G1bf, bF2, bD2, G0, st2);
    k_fin<<<dim3(2), 64, 0, stream>>>(st2, gF2, btF2, gD2, btD2, coef2, H2D);
    k_pool<<<dim3(BSZ, 2), 64, 0, stream>>>(G0, coef2, featF, featD);
    k_heads<<<BSZ, 128, 0, stream>>>(featF, featD, WlinF, blinF, WlinD, blinD,
                                     Wlin, blin, (float*)d_out);
}

// Round 4
// 525.880 us; speedup vs baseline: 5.1720x; 1.6238x over previous
//
#include <hip/hip_runtime.h>
#include <math.h>

// ---------------- problem constants ----------------
#define NN    36864        // N = B*V
#define F0    1025
#define H1D   256
#define H2D   64
#define VV    36
#define SS    12
#define BSZ   1024         // N / V
#define BN_EPS 1e-5f

#define KT1   17                       // ceil(1025/64)
#define WT1_STRIDE  ((size_t)4*17*8192)     // bf16 elems per branch (W1 tiles)
#define YBF_STRIDE  ((size_t)288*4*8192)    // bf16 elems per branch (Y tiles)
#define WT2_STRIDE  ((size_t)4*8192)

typedef __bf16 bf16x8 __attribute__((ext_vector_type(8)));
typedef __bf16 bf16x4 __attribute__((ext_vector_type(4)));
typedef float  f32x4  __attribute__((ext_vector_type(4)));

__device__ __forceinline__ float4 ld4u(const float* p) {
    float4 v;
    __builtin_memcpy(&v, p, 16);   // 4B-aligned OK on gfx9+ (unaligned access)
    return v;
}

// ---------------- utility ----------------
__global__ void k_zero(float* __restrict__ p, int n) {
    int i = blockIdx.x * blockDim.x + threadIdx.x;
    if (i < n) p[i] = 0.f;
}

__global__ void k_deg(const int* __restrict__ eiF, const int* __restrict__ eiD,
                      int E, float* __restrict__ degAll) {
    int br = blockIdx.y;
    const int* src = br ? eiD : eiF;
    float* deg = degAll + (size_t)br * NN;
    int e = blockIdx.x * blockDim.x + threadIdx.x;
    if (e < E) atomicAdd(&deg[src[e]], 1.f);
}

__device__ __forceinline__ float dinv_f(float d) {
    return d > 0.f ? rsqrtf(fmaxf(d, 1.f)) : 0.f;
}

__global__ void k_scatter(const int* __restrict__ eiF, const int* __restrict__ eiD,
                          int E, const float* __restrict__ degAll, float* __restrict__ AdjAll) {
    int br = blockIdx.y;
    const int* src = br ? eiD : eiF;
    const int* dst = src + E;
    const float* deg = degAll + (size_t)br * NN;
    float* Adj = AdjAll + (size_t)br * BSZ * (VV * VV);
    int e = blockIdx.x * blockDim.x + threadIdx.x;
    if (e >= E) return;
    int s = src[e], d = dst[e];
    float w = -dinv_f(deg[s]) * dinv_f(deg[d]);
    int blk = s / VV;
    atomicAdd(&Adj[(size_t)blk * (VV * VV) + (d - blk * VV) * VV + (s - blk * VV)], w);
}

// ---------------- prep W: [bn][kt][128c x 64k] tiled+swizzled, both branches ----------------
__global__ __launch_bounds__(256) void k_prepW(
    const float* __restrict__ WaF, const float* __restrict__ WbF,
    const float* __restrict__ WaD, const float* __restrict__ WbD,
    __bf16* __restrict__ Wt, int K, int nkt, int split, int ldw, size_t brStride) {
    int br = blockIdx.y;
    const float* Wa = br ? WaD : WaF;
    const float* Wb = br ? WbD : WbF;
    __bf16* out = Wt + (size_t)br * brStride;

    int id = blockIdx.x * 256 + threadIdx.x;
    int gpc = nkt * 8;
    int c = id / gpc, gi = id - c * gpc;
    int kt = gi >> 3, g = gi & 7;
    int k0 = kt * 64 + g * 8;
    const float* src = (c < split) ? (Wa + c) : (Wb + (c - split));
    bf16x8 ov;
#pragma unroll
    for (int j = 0; j < 8; ++j) {
        int k = k0 + j;
        float v = (k < K) ? src[(size_t)k * ldw] : 0.f;
        ov[j] = (__bf16)v;
    }
    int r = c & 127, bn = c >> 7;
    size_t dst = ((size_t)(bn * nkt + kt) << 13) + r * 64 + ((g ^ (r & 7)) << 3);
    *(bf16x8*)(out + dst) = ov;
}

// ---------------- fused GEMM1: H = (x+Temb+Semb) @ [W0|W1], embedding+cvt fused ----------------
// grid (288, 2, 2): bm (128 rows), cy (256-col half), br. 512 threads = 8 waves (2x4),
// wave tile 64x64, acc 4x4 frags of 16x16x32. LDS double-buffered: A reg-staged (ds_write),
// B via global_load_lds from pre-swizzled Wt1 tiles.
__global__ __launch_bounds__(512) void k_gemm1f(
    const float* __restrict__ xF, const float* __restrict__ xD,
    const float* __restrict__ TembF, const float* __restrict__ SembF,
    const float* __restrict__ TembD, const float* __restrict__ SembD,
    const __bf16* __restrict__ Wt1All,
    float* __restrict__ H0All, __bf16* __restrict__ H1All) {
    __shared__ __align__(16) __bf16 As[2 * 8192];    // 32 KB
    __shared__ __align__(16) __bf16 Bs[2 * 16384];   // 64 KB
    const int tid = threadIdx.x;
    const int lane = tid & 63, wid = tid >> 6;
    const int bm = blockIdx.x, cy = blockIdx.y, br = blockIdx.z;
    const float* x    = br ? xD : xF;
    const float* Temb = br ? TembD : TembF;
    const float* Semb = br ? SembD : SembF;
    const __bf16* Wt = Wt1All + (size_t)br * WT1_STRIDE;
    float*  H0 = H0All + (size_t)br * NN * H1D;
    __bf16* H1 = H1All + (size_t)br * NN * H1D;

    const int wr = wid >> 2, wc = wid & 3;
    const int l15 = lane & 15, lg = lane >> 4;
    const int bn0 = cy * 2;

    // ---- A staging map: wave covers rows wid*16..+16; lane -> (rowgroup, 16B k-chunk) ----
    const int kc = (lane & 15) * 4;        // k offset within 64-k tile (float granularity)
    const float *pxr[4], *ptr_[4], *psr[4];
    int dso[4];
#pragma unroll
    for (int i = 0; i < 4; ++i) {
        int r = wid * 16 + i * 4 + (lane >> 4);
        int g = bm * 128 + r;
        int lv = g % VV;
        pxr[i]  = x    + (size_t)g * F0 + kc;
        ptr_[i] = Temb + (size_t)(lv / SS) * F0 + kc;
        psr[i]  = Semb + (size_t)(lv % SS) * F0 + kc;
        dso[i] = r * 64 + (((kc >> 3) ^ (r & 7)) << 3) + (kc & 4);
    }

    // ---- fragment LDS offsets (swizzled) ----
    int offA[2][4], offB[2][4];
#pragma unroll
    for (int kk = 0; kk < 2; ++kk) {
#pragma unroll
        for (int m = 0; m < 4; ++m) {
            int rowA = wr * 64 + m * 16 + l15;
            offA[kk][m] = rowA * 64 + (((kk * 4 + lg) ^ (rowA & 7)) << 3);
        }
#pragma unroll
        for (int n = 0; n < 4; ++n) {
            int col = wc * 64 + n * 16 + l15;      // 0..255
            offB[kk][n] = (col >> 7) * 8192 + (col & 127) * 64
                          + (((kk * 4 + lg) ^ (col & 7)) << 3);
        }
    }

    f32x4 acc[4][4];
#pragma unroll
    for (int m = 0; m < 4; ++m)
#pragma unroll
        for (int n = 0; n < 4; ++n) acc[m][n] = (f32x4){0.f, 0.f, 0.f, 0.f};

    auto stage = [&](int kt, int buf) {
        // B: two 16KB pre-swizzled tiles -> linear LDS; 4 x 1KB chunks per wave
#pragma unroll
        for (int cc = 0; cc < 4; ++cc) {
            int q = (wid * 4 + cc) * 512;          // elem offset in 16384-elem buffer
            int h = q >> 13, qi = q & 8191;        // wave-uniform
            const __bf16* src = Wt + (((size_t)(bn0 + h) * KT1 + kt) << 13)
                                + qi + (lane << 3);
            __builtin_amdgcn_global_load_lds(
                (const __attribute__((address_space(1))) void*)src,
                (__attribute__((address_space(3))) void*)(Bs + buf * 16384 + q), 16, 0, 0);
        }
        // A: embedding-add + bf16 cvt + swizzled ds_write (coalesced float4 reads)
        int ko = kt * 64;
        int kb = ko + kc;
#pragma unroll
        for (int i = 0; i < 4; ++i) {
            float va[4];
            if (kb + 3 < F0) {
                float4 a = ld4u(pxr[i] + ko);
                float4 b = ld4u(ptr_[i] + ko);
                float4 c = ld4u(psr[i] + ko);
                va[0] = a.x + b.x + c.x; va[1] = a.y + b.y + c.y;
                va[2] = a.z + b.z + c.z; va[3] = a.w + b.w + c.w;
            } else {
#pragma unroll
                for (int j = 0; j < 4; ++j) {
                    int k = kb + j;
                    va[j] = (k < F0) ? (pxr[i][ko + j] + ptr_[i][ko + j] + psr[i][ko + j])
                                     : 0.f;
                }
            }
            bf16x4 w;
            w[0] = (__bf16)va[0]; w[1] = (__bf16)va[1];
            w[2] = (__bf16)va[2]; w[3] = (__bf16)va[3];
            *(bf16x4*)(As + buf * 8192 + dso[i]) = w;
        }
    };

    stage(0, 0);
    for (int kt = 0; kt < KT1; ++kt) {
        int cur = kt & 1;
        __syncthreads();                       // buf[cur] fully staged (vm+lgkm drained)
        if (kt + 1 < KT1) stage(kt + 1, cur ^ 1);
        const __bf16* Ab = As + cur * 8192;
        const __bf16* Bb = Bs + cur * 16384;
#pragma unroll
        for (int kk = 0; kk < 2; ++kk) {
            bf16x8 af[4], bb[4];
#pragma unroll
            for (int m = 0; m < 4; ++m) af[m] = *(const bf16x8*)(Ab + offA[kk][m]);
#pragma unroll
            for (int n = 0; n < 4; ++n) bb[n] = *(const bf16x8*)(Bb + offB[kk][n]);
#pragma unroll
            for (int m = 0; m < 4; ++m)
#pragma unroll
                for (int n = 0; n < 4; ++n)
                    acc[m][n] = __builtin_amdgcn_mfma_f32_16x16x32_bf16(
                        af[m], bb[n], acc[m][n], 0, 0, 0);
        }
    }

    // epilogue: frag row = lg*4+j, col = l15
    const int cr = lg * 4;
#pragma unroll
    for (int m = 0; m < 4; ++m) {
        int grow = bm * 128 + wr * 64 + m * 16 + cr;
#pragma unroll
        for (int n = 0; n < 4; ++n) {
            int gc = cy * 256 + wc * 64 + n * 16 + l15;
#pragma unroll
            for (int j = 0; j < 4; ++j) {
                int r = grow + j;
                if (gc < 256) H0[(size_t)r * H1D + gc] = acc[m][n][j];
                else          H1[(size_t)r * H1D + (gc - 256)] = (__bf16)acc[m][n][j];
            }
        }
    }
}

// ---------------- prep Y (GEMM2 A): bf16(relu(Y*sA+sB)) tiled+swizzled, coalesced ----------
__global__ __launch_bounds__(256) void k_prepY(
    const float* __restrict__ YAll, const float* __restrict__ coefAll,
    __bf16* __restrict__ YbfAll) {
    int br = blockIdx.y;
    const float* Y = YAll + (size_t)br * NN * H1D;
    const float* coef = coefAll + (size_t)br * 2 * H1D;
    __bf16* out = YbfAll + (size_t)br * YBF_STRIDE;

    int id = blockIdx.x * 256 + threadIdx.x;   // 36864 rows * 64 chunks
    int row = id >> 6;
    int kcol = (id & 63) * 4;                  // 0..252 within H1D
    float4 y  = *reinterpret_cast<const float4*>(Y + (size_t)row * H1D + kcol);
    float4 cA = *reinterpret_cast<const float4*>(coef + kcol);
    float4 cB = *reinterpret_cast<const float4*>(coef + H1D + kcol);
    bf16x4 w;
    w[0] = (__bf16)fmaxf(fmaf(y.x, cA.x, cB.x), 0.f);
    w[1] = (__bf16)fmaxf(fmaf(y.y, cA.y, cB.y), 0.f);
    w[2] = (__bf16)fmaxf(fmaf(y.z, cA.z, cB.z), 0.f);
    w[3] = (__bf16)fmaxf(fmaf(y.w, cA.w, cB.w), 0.f);
    int r = row & 127, bm = row >> 7;
    int kt = kcol >> 6, kin = kcol & 63, g = kin >> 3;
    size_t dst = ((size_t)(bm * 4 + kt) << 13) + r * 64 + ((g ^ (r & 7)) << 3) + (kin & 4);
    *(bf16x4*)(out + dst) = w;
}

// ---------------- MFMA GEMM (layer 2): C[128x128 per block] = At @ Bt^T ----------------
__global__ __launch_bounds__(256) void k_mfma_gemm(
    const __bf16* __restrict__ AtAll, const __bf16* __restrict__ BtAll,
    float* __restrict__ outAAll, __bf16* __restrict__ outBAll,
    int KT, int split, int ldc,
    size_t strideAt, size_t strideBt, size_t strideOutA, size_t strideOutB) {
    __shared__ __align__(16) __bf16 As[8192];
    __shared__ __align__(16) __bf16 Bs[8192];
    const int tid = threadIdx.x;
    const int lane = tid & 63, wid = tid >> 6;
    const int bm = blockIdx.x, bn = blockIdx.y, br = blockIdx.z;
    const int wr = wid >> 1, wc = wid & 1;
    const int l15 = lane & 15, lg = lane >> 4;

    const __bf16* At = AtAll + (size_t)br * strideAt;
    const __bf16* Bt = BtAll + (size_t)br * strideBt;
    float*  outA = outAAll + (size_t)br * strideOutA;
    __bf16* outB = outBAll + (size_t)br * strideOutB;

    f32x4 acc[4][4];
#pragma unroll
    for (int m = 0; m < 4; ++m)
#pragma unroll
        for (int n = 0; n < 4; ++n) acc[m][n] = (f32x4){0.f, 0.f, 0.f, 0.f};

    int offA[2][4], offB[2][4];
#pragma unroll
    for (int kk = 0; kk < 2; ++kk)
#pragma unroll
        for (int m = 0; m < 4; ++m) {
            int rowA = wr * 64 + m * 16 + l15;
            offA[kk][m] = rowA * 64 + (((kk * 4 + lg) ^ (rowA & 7)) << 3);
            int rowB = wc * 64 + m * 16 + l15;
            offB[kk][m] = rowB * 64 + (((kk * 4 + lg) ^ (rowB & 7)) << 3);
        }

    const __bf16* pA = At + ((size_t)bm * KT << 13) + (lane << 3);
    const __bf16* pB = Bt + ((size_t)bn * KT << 13) + (lane << 3);

    for (int kt = 0; kt < KT; ++kt) {
        const __bf16* sA = pA + ((size_t)kt << 13);
        const __bf16* sB = pB + ((size_t)kt << 13);
#pragma unroll
        for (int c = 0; c < 4; ++c) {
            int q = (wid * 4 + c) * 512;
            __builtin_amdgcn_global_load_lds(
                (const __attribute__((address_space(1))) void*)(sA + q),
                (__attribute__((address_space(3))) void*)(As + q), 16, 0, 0);
            __builtin_amdgcn_global_load_lds(
                (const __attribute__((address_space(1))) void*)(sB + q),
                (__attribute__((address_space(3))) void*)(Bs + q), 16, 0, 0);
        }
        __syncthreads();
#pragma unroll
        for (int kk = 0; kk < 2; ++kk) {
            bf16x8 af[4], bb[4];
#pragma unroll
            for (int m = 0; m < 4; ++m) af[m] = *(const bf16x8*)(&As[offA[kk][m]]);
#pragma unroll
            for (int n = 0; n < 4; ++n) bb[n] = *(const bf16x8*)(&Bs[offB[kk][n]]);
#pragma unroll
            for (int m = 0; m < 4; ++m)
#pragma unroll
                for (int n = 0; n < 4; ++n)
                    acc[m][n] = __builtin_amdgcn_mfma_f32_16x16x32_bf16(
                        af[m], bb[n], acc[m][n], 0, 0, 0);
        }
        __syncthreads();
    }

    const int cr = lg * 4, cc = l15;
#pragma unroll
    for (int m = 0; m < 4; ++m) {
        int grow = bm * 128 + wr * 64 + m * 16 + cr;
#pragma unroll
        for (int n = 0; n < 4; ++n) {
            int col = bn * 128 + wc * 64 + n * 16 + cc;
#pragma unroll
            for (int j = 0; j < 4; ++j) {
                int r = grow + j;
                if (col < split) outA[(size_t)r * ldc + col] = acc[m][n][j];
                else             outB[(size_t)r * ldc + (col - split)] = (__bf16)acc[m][n][j];
            }
        }
    }
}

// ---------------- combine1 + BN stats: Y = H0 + Adj@H1 + b; accumulate col sums ----------------
__global__ __launch_bounds__(256) void k_combine_stats1(
    const float* __restrict__ AdjAll, const __bf16* __restrict__ H1All,
    const float* __restrict__ bF, const float* __restrict__ bD,
    float* __restrict__ YAll, float* __restrict__ stAll) {
    __shared__ float Adj_s[VV * VV];
    __shared__ float red[256 * 9];
    int b = blockIdx.x, br = blockIdx.y, t = threadIdx.x;
    const float* Adj = AdjAll + ((size_t)br * BSZ + b) * (VV * VV);
    const __bf16* h1 = H1All + ((size_t)br * NN + (size_t)b * VV) * H1D;
    float* yb = YAll + ((size_t)br * NN + (size_t)b * VV) * H1D;
    float* st = stAll + (size_t)br * 2 * H1D;
    const float* bias = br ? bD : bF;

    for (int e = t; e < VV * VV; e += 256) Adj_s[e] = Adj[e];
    __syncthreads();

    int c0 = (t & 63) * 4, r0 = t >> 6;
    float4 bv = *reinterpret_cast<const float4*>(bias + c0);
    float acc[9][4];
#pragma unroll
    for (int i = 0; i < 9; ++i) {
        float4 y = *reinterpret_cast<const float4*>(yb + (size_t)(r0 + 4 * i) * H1D + c0);
        acc[i][0] = y.x + bv.x; acc[i][1] = y.y + bv.y;
        acc[i][2] = y.z + bv.z; acc[i][3] = y.w + bv.w;
    }
#pragma unroll 4
    for (int j = 0; j < VV; ++j) {
        bf16x4 hv = *reinterpret_cast<const bf16x4*>(h1 + (size_t)j * H1D + c0);
        float h0 = (float)hv[0], h1f = (float)hv[1], h2 = (float)hv[2], h3 = (float)hv[3];
#pragma unroll
        for (int i = 0; i < 9; ++i) {
            float a = Adj_s[(r0 + 4 * i) * VV + j];
            acc[i][0] = fmaf(a, h0, acc[i][0]);
            acc[i][1] = fmaf(a, h1f, acc[i][1]);
            acc[i][2] = fmaf(a, h2, acc[i][2]);
            acc[i][3] = fmaf(a, h3, acc[i][3]);
        }
    }
    float s[4] = {0, 0, 0, 0}, s2[4] = {0, 0, 0, 0};
#pragma unroll
    for (int i = 0; i < 9; ++i) {
        *reinterpret_cast<float4*>(yb + (size_t)(r0 + 4 * i) * H1D + c0) =
            make_float4(acc[i][0], acc[i][1], acc[i][2], acc[i][3]);
#pragma unroll
        for (int k = 0; k < 4; ++k) { s[k] += acc[i][k]; s2[k] += acc[i][k] * acc[i][k]; }
    }
#pragma unroll
    for (int k = 0; k < 4; ++k) { red[t * 9 + k] = s[k]; red[t * 9 + 4 + k] = s2[k]; }
    __syncthreads();
    {
        int cg = t >> 2, k = t & 3;
        float ss = 0.f, ss2 = 0.f;
#pragma unroll
        for (int q = 0; q < 4; ++q) {
            ss  += red[(q * 64 + cg) * 9 + k];
            ss2 += red[(q * 64 + cg) * 9 + 4 + k];
        }
        atomicAdd(&st[t], ss);
        atomicAdd(&st[H1D + t], ss2);
    }
}

// ---------------- combine2 + BN stats ----------------
__global__ __launch_bounds__(256) void k_combine_stats2(
    const float* __restrict__ AdjAll, const __bf16* __restrict__ G1All,
    const float* __restrict__ bF, const float* __restrict__ bD,
    float* __restrict__ YAll, float* __restrict__ stAll) {
    __shared__ float Adj_s[VV * VV];
    __shared__ float red[256 * 9];
    int b = blockIdx.x, br = blockIdx.y, t = threadIdx.x;
    const float* Adj = AdjAll + ((size_t)br * BSZ + b) * (VV * VV);
    const __bf16* g1 = G1All + ((size_t)br * NN + (size_t)b * VV) * H2D;
    float* yb = YAll + ((size_t)br * NN + (size_t)b * VV) * H2D;
    float* st = stAll + (size_t)br * 2 * H2D;
    const float* bias = br ? bD : bF;

    for (int e = t; e < VV * VV; e += 256) Adj_s[e] = Adj[e];
    __syncthreads();

    int c0 = (t & 15) * 4, r0 = t >> 4;          // r0 in 0..15
    int nr = (r0 < 4) ? 3 : 2;                   // rows r0, r0+16, (r0+32)
    float4 bv = *reinterpret_cast<const float4*>(bias + c0);
    float acc[3][4];
    for (int i = 0; i < nr; ++i) {
        float4 y = *reinterpret_cast<const float4*>(yb + (size_t)(r0 + 16 * i) * H2D + c0);
        acc[i][0] = y.x + bv.x; acc[i][1] = y.y + bv.y;
        acc[i][2] = y.z + bv.z; acc[i][3] = y.w + bv.w;
    }
#pragma unroll 4
    for (int j = 0; j < VV; ++j) {
        bf16x4 hv = *reinterpret_cast<const bf16x4*>(g1 + (size_t)j * H2D + c0);
        float h0 = (float)hv[0], h1f = (float)hv[1], h2 = (float)hv[2], h3 = (float)hv[3];
        for (int i = 0; i < nr; ++i) {
            float a = Adj_s[(r0 + 16 * i) * VV + j];
            acc[i][0] = fmaf(a, h0, acc[i][0]);
            acc[i][1] = fmaf(a, h1f, acc[i][1]);
            acc[i][2] = fmaf(a, h2, acc[i][2]);
            acc[i][3] = fmaf(a, h3, acc[i][3]);
        }
    }
    float s[4] = {0, 0, 0, 0}, s2[4] = {0, 0, 0, 0};
    for (int i = 0; i < nr; ++i) {
        *reinterpret_cast<float4*>(yb + (size_t)(r0 + 16 * i) * H2D + c0) =
            make_float4(acc[i][0], acc[i][1], acc[i][2], acc[i][3]);
#pragma unroll
        for (int k = 0; k < 4; ++k) { s[k] += acc[i][k]; s2[k] += acc[i][k] * acc[i][k]; }
    }
#pragma unroll
    for (int k = 0; k < 4; ++k) { red[t * 9 + k] = s[k]; red[t * 9 + 4 + k] = s2[k]; }
    __syncthreads();
    if (t < 2 * H2D) {
        int cg = (t & 63) >> 2, k = t & 3, which = t >> 6;
        float ss = 0.f;
#pragma unroll
        for (int q = 0; q < 16; ++q) ss += red[(q * 16 + cg) * 9 + which * 4 + k];
        atomicAdd(&st[(t >> 6) * H2D + (t & 63)], ss);
    }
}

// ---------------- finalize BN coefficients (both branches) ----------------
__global__ void k_fin(const float* __restrict__ stAll,
                      const float* __restrict__ gF, const float* __restrict__ btF,
                      const float* __restrict__ gD, const float* __restrict__ btD,
                      float* __restrict__ coefAll, int H) {
    int br = blockIdx.x, t = threadIdx.x;
    const float* st = stAll + (size_t)br * 2 * H;
    float* coef = coefAll + (size_t)br * 2 * H;
    const float* g = br ? gD : gF;
    const float* bt = br ? btD : btF;
    if (t >= H) return;
    float mu = st[t] / (float)NN;
    float var = st[H + t] / (float)NN - mu * mu;
    float sA = g[t] * rsqrtf(var + BN_EPS);
    coef[t] = sA;
    coef[H + t] = bt[t] - mu * sA;
}

// ---------------- pool ----------------
__global__ __launch_bounds__(64) void k_pool(const float* __restrict__ Y2All,
                                             const float* __restrict__ coefAll,
                                             float* __restrict__ featF,
                                             float* __restrict__ featD) {
    int b = blockIdx.x, br = blockIdx.y, c = threadIdx.x;
    const float* Y2 = Y2All + (size_t)br * NN * H2D;
    const float* coef = coefAll + (size_t)br * 2 * H2D;
    float* feat = br ? featD : featF;
    float sA = coef[c], sB = coef[H2D + c];
    float mx = -1e30f, sm = 0.f;
    const float* yb = Y2 + ((size_t)b * VV + SS) * H2D + c;
#pragma unroll
    for (int i = 0; i < SS; ++i) {
        float v = fmaxf(fmaf(yb[i * H2D], sA, sB), 0.f);
        mx = fmaxf(mx, v);
        sm += v;
    }
    feat[b * 128 + c] = mx;
    feat[b * 128 + 64 + c] = sm * (1.f / 12.f);
}

// ---------------- heads ----------------
__global__ __launch_bounds__(128) void k_heads(
    const float* __restrict__ featF, const float* __restrict__ featD,
    const float* __restrict__ WlinF, const float* __restrict__ blinF,
    const float* __restrict__ WlinD, const float* __restrict__ blinD,
    const float* __restrict__ Wlin, const float* __restrict__ blin,
    float* __restrict__ out) {
    __shared__ float sF[128], sD[128], lg[24];
    int r = blockIdx.x, t = threadIdx.x;
    sF[t] = featF[r * 128 + t];
    sD[t] = featD[r * 128 + t];
    __syncthreads();
    float* fus = out + 10240 + (size_t)r * 256;
    fus[t] = sF[t];
    fus[128 + t] = sD[t];
    if (t < 5) {
        float a = blinF[t];
        for (int k = 0; k < 128; ++k) a += sF[k] * WlinF[k * 5 + t];
        lg[t] = a;
    } else if (t >= 8 && t < 13) {
        int j = t - 8;
        float a = blinD[j];
        for (int k = 0; k < 128; ++k) a += sD[k] * WlinD[k * 5 + j];
        lg[8 + j] = a;
    } else if (t >= 16 && t < 21) {
        int j = t - 16;
        float a = blin[j];
        for (int k = 0; k < 128; ++k) a += sF[k] * Wlin[k * 5 + j];
        for (int k = 0; k < 128; ++k) a += sD[k] * Wlin[(128 + k) * 5 + j];
        lg[16 + j] = a;
    }
    __syncthreads();
    if (t < 15) {
        int grp = t / 5, j = t % 5;
        const float* l = &lg[grp * 8];
        float m = l[0];
#pragma unroll
        for (int k = 1; k < 5; ++k) m = fmaxf(m, l[k]);
        float den = 0.f;
#pragma unroll
        for (int k = 0; k < 5; ++k) den += expf(l[k] - m);
        float v = expf(l[j] - m) / den;
        float* dst = (grp == 0) ? out : (grp == 1 ? out + 5120 : out + 272384);
        dst[r * 5 + j] = v;
    }
}

// ---------------- launch ----------------
extern "C" void kernel_launch(void* const* d_in, const int* in_sizes, int n_in,
                              void* d_out, int out_size, void* d_ws, size_t ws_size,
                              hipStream_t stream) {
    const float* xF    = (const float*)d_in[0];
    const float* xD    = (const float*)d_in[1];
    const int*   eiF   = (const int*)d_in[2];
    const int*   eiD   = (const int*)d_in[3];
    const float* TembF = (const float*)d_in[4];
    const float* SembF = (const float*)d_in[5];
    const float* TembD = (const float*)d_in[6];
    const float* SembD = (const float*)d_in[7];
    const float* W0F1  = (const float*)d_in[8];
    const float* W1F1  = (const float*)d_in[9];
    const float* bF1   = (const float*)d_in[10];
    const float* gF1   = (const float*)d_in[11];
    const float* btF1  = (const float*)d_in[12];
    const float* W0F2  = (const float*)d_in[13];
    const float* W1F2  = (const float*)d_in[14];
    const float* bF2   = (const float*)d_in[15];
    const float* gF2   = (const float*)d_in[16];
    const float* btF2  = (const float*)d_in[17];
    const float* W0D1  = (const float*)d_in[18];
    const float* W1D1  = (const float*)d_in[19];
    const float* bD1   = (const float*)d_in[20];
    const float* gD1   = (const float*)d_in[21];
    const float* btD1  = (const float*)d_in[22];
    const float* W0D2  = (const float*)d_in[23];
    const float* W1D2  = (const float*)d_in[24];
    const float* bD2   = (const float*)d_in[25];
    const float* gD2   = (const float*)d_in[26];
    const float* btD2  = (const float*)d_in[27];
    const float* WlinF = (const float*)d_in[28];
    const float* blinF = (const float*)d_in[29];
    const float* WlinD = (const float*)d_in[30];
    const float* blinD = (const float*)d_in[31];
    const float* Wlin  = (const float*)d_in[32];
    const float* blin  = (const float*)d_in[33];

    const int E = in_sizes[2] / 2;   // 589824 per branch

    // -------- workspace layout (float units); [2] = branch-major --------
    float* ws = (float*)d_ws;
    size_t o = 0;
    float*  H0   = ws + o;              o += (size_t)2 * NN * H1D;          // 75.5 MB
    __bf16* H1bf = (__bf16*)(ws + o);   o += (size_t)2 * NN * H1D / 2;      // 37.7 MB
    __bf16* Ybf  = (__bf16*)(ws + o);   o += (size_t)2 * YBF_STRIDE / 2;    // 37.7 MB
    float*  G0   = ws + o;              o += (size_t)2 * NN * H2D;          // 18.9 MB
    __bf16* G1bf = (__bf16*)(ws + o);   o += (size_t)2 * NN * H2D / 2;      // 9.4 MB
    __bf16* Wt1  = (__bf16*)(ws + o);   o += (size_t)2 * WT1_STRIDE / 2;
    __bf16* Wt2  = (__bf16*)(ws + o);   o += (size_t)2 * WT2_STRIDE / 2;
    float*  Adj  = ws + o;              o += (size_t)2 * BSZ * VV * VV;     // zero span start
    float*  deg  = ws + o;              o += (size_t)2 * NN;
    float*  st1  = ws + o;              o += 2 * 2 * H1D;
    float*  st2  = ws + o;              o += 2 * 2 * H2D;                   // zero span end
    float*  coef1 = ws + o;             o += 2 * 2 * H1D;
    float*  coef2 = ws + o;             o += 2 * 2 * H2D;
    float*  featF = ws + o;             o += (size_t)BSZ * 128;
    float*  featD = ws + o;             o += (size_t)BSZ * 128;

    const int zeroN = 2 * (BSZ * VV * VV + NN + 2 * H1D + 2 * H2D);

    k_zero<<<(zeroN + 255) / 256, 256, 0, stream>>>(Adj, zeroN);
    k_deg<<<dim3((E + 255) / 256, 2), 256, 0, stream>>>(eiF, eiD, E, deg);
    k_scatter<<<dim3((E + 255) / 256, 2), 256, 0, stream>>>(eiF, eiD, E, deg, Adj);
    k_prepW<<<dim3(272, 2), 256, 0, stream>>>(W0F1, W1F1, W0D1, W1D1, Wt1,
                                              F0, 17, 256, H1D, WT1_STRIDE);
    k_prepW<<<dim3(16, 2), 256, 0, stream>>>(W0F2, W1F2, W0D2, W1D2, Wt2,
                                             H1D, 4, 64, H2D, WT2_STRIDE);
    k_gemm1f<<<dim3(288, 2, 2), 512, 0, stream>>>(
        xF, xD, TembF, SembF, TembD, SembD, Wt1, H0, H1bf);
    k_combine_stats1<<<dim3(BSZ, 2), 256, 0, stream>>>(Adj, H1bf, bF1, bD1, H0, st1);
    k_fin<<<dim3(2), 256, 0, stream>>>(st1, gF1, btF1, gD1, btD1, coef1, H1D);
    k_prepY<<<dim3(9216, 2), 256, 0, stream>>>(H0, coef1, Ybf);
    k_mfma_gemm<<<dim3(288, 1, 2), 256, 0, stream>>>(
        Ybf, Wt2, G0, G1bf, 4, 64, H2D,
        YBF_STRIDE, WT2_STRIDE, (size_t)NN * H2D, (size_t)NN * H2D);
    k_combine_stats2<<<dim3(BSZ, 2), 256, 0, stream>>>(Adj, G1bf, bF2, bD2, G0, st2);
    k_fin<<<dim3(2), 64, 0, stream>>>(st2, gF2, btF2, gD2, btD2, coef2, H2D);
    k_pool<<<dim3(BSZ, 2), 64, 0, stream>>>(G0, coef2, featF, featD);
    k_heads<<<BSZ, 128, 0, stream>>>(featF, featD, WlinF, blinF, WlinD, blinD,
                                     Wlin, blin, (float*)d_out);
}